// Round 7
// baseline (439.226 us; speedup 1.0000x reference)
//
#include <hip/hip_runtime.h>

static constexpr int E0 = 160000;   // level-0 edges
static constexpr int NL0 = 20000;   // nodes level 0
static constexpr int NL1 = 6912;    // 4 * 12^3   (voxel 20)
static constexpr int NL2 = 2048;    // 4 * 8^3    (voxel 30)
static constexpr int NL3 = 500;     // 4 * 5^3    (voxel 50)

typedef short bf16x8 __attribute__((ext_vector_type(8)));
typedef float f32x4 __attribute__((ext_vector_type(4)));

// ---------- helpers ----------
__device__ __forceinline__ unsigned f2ord(float f) {
  unsigned u = __float_as_uint(f);
  return (u & 0x80000000u) ? ~u : (u | 0x80000000u);
}
__device__ __forceinline__ float ord2f(unsigned u) {
  unsigned v = (u & 0x80000000u) ? (u & 0x7fffffffu) : ~u;
  return __uint_as_float(v);
}
__device__ __forceinline__ float eluf(float x) { return x > 0.f ? x : expm1f(x); }
__device__ __forceinline__ void basis8(float u0, float u1, float u2, float* w) {
  float a0 = 1.f - u0, a1 = 1.f - u1, a2 = 1.f - u2;
  w[0] = a0*a1*a2; w[1] = a0*a1*u2; w[2] = a0*u1*a2; w[3] = a0*u1*u2;
  w[4] = u0*a1*a2; w[5] = u0*a1*u2; w[6] = u0*u1*a2; w[7] = u0*u1*u2;
}
__device__ __forceinline__ unsigned short f2b(float f) {  // fp32 -> bf16 RNE
  unsigned u = __float_as_uint(f);
  return (unsigned short)((u + 0x7fffu + ((u >> 16) & 1u)) >> 16);
}
__device__ __forceinline__ float b2f(unsigned short h) {
  return __uint_as_float(((unsigned)h) << 16);
}
__device__ __forceinline__ int clampi(int v, int lo, int hi) {
  return v < lo ? lo : (v > hi ? hi : v);
}

// ---------- MFMA 64x64 tile core (bf16 hi/lo 3-pass) ----------
__device__ __forceinline__ void mfma_tile(const unsigned short* __restrict__ Ah,
    const unsigned short* __restrict__ Al, const unsigned short* __restrict__ Bh,
    const unsigned short* __restrict__ Bl, int M, long K, int m0, int n0,
    int kbeg, int ksl, char* smem, f32x4* acc) {
  auto Ash = (unsigned short (*)[40])(smem);
  auto Asl = (unsigned short (*)[40])(smem + 5120);
  auto Bsh = (unsigned short (*)[40])(smem + 10240);
  auto Bsl = (unsigned short (*)[40])(smem + 15360);
  int t = threadIdx.x;
  int r = t >> 2, sg = (t & 3) * 8;
  int w = t >> 6, lane = t & 63;
  int ar = (w << 4) + (lane & 15), kq = (lane >> 4) << 3;
  for (int kt = 0; kt < ksl; kt += 32) {
    bf16x8 va = {}, vl = {};
    if (m0 + r < M) {
      long ga = (long)(m0 + r) * K + kbeg + kt + sg;
      va = *(const bf16x8*)&Ah[ga];
      vl = *(const bf16x8*)&Al[ga];
    }
    *(bf16x8*)&Ash[r][sg] = va;
    *(bf16x8*)&Asl[r][sg] = vl;
    long gb = (long)(n0 + r) * K + kbeg + kt + sg;
    *(bf16x8*)&Bsh[r][sg] = *(const bf16x8*)&Bh[gb];
    *(bf16x8*)&Bsl[r][sg] = *(const bf16x8*)&Bl[gb];
    __syncthreads();
    bf16x8 ah = *(const bf16x8*)&Ash[ar][kq];
    bf16x8 al = *(const bf16x8*)&Asl[ar][kq];
    #pragma unroll
    for (int nt = 0; nt < 4; nt++) {
      int br = (nt << 4) + (lane & 15);
      bf16x8 bh = *(const bf16x8*)&Bsh[br][kq];
      bf16x8 bl = *(const bf16x8*)&Bsl[br][kq];
      acc[nt] = __builtin_amdgcn_mfma_f32_16x16x32_bf16(al, bh, acc[nt], 0, 0, 0);
      acc[nt] = __builtin_amdgcn_mfma_f32_16x16x32_bf16(ah, bl, acc[nt], 0, 0, 0);
      acc[nt] = __builtin_amdgcn_mfma_f32_16x16x32_bf16(ah, bh, acc[nt], 0, 0, 0);
    }
    __syncthreads();
  }
}

// ---------- k_prep: L0 deg count + absmax + edge records + weight prep ----------
__global__ __launch_bounds__(256)
void k_prep(const int* __restrict__ src0, const int* __restrict__ dst0,
            const float* __restrict__ pos0, const float* __restrict__ x0,
            int* __restrict__ degi, int4* __restrict__ erec0u, float* __restrict__ mbuf,
            const float* __restrict__ W1, const float* __restrict__ Wr1, float* __restrict__ wc1,
            const float* __restrict__ W2, const float* __restrict__ Wr2,
            const float* __restrict__ W3, const float* __restrict__ Wr3,
            const float* __restrict__ W4, const float* __restrict__ Wr4,
            unsigned short* __restrict__ w2h, unsigned short* __restrict__ w2l,
            unsigned short* __restrict__ w3h, unsigned short* __restrict__ w3l,
            unsigned short* __restrict__ w4h, unsigned short* __restrict__ w4l) {
  __shared__ __align__(16) float T[64][65];
  __shared__ float red[4];
  int tid = blockIdx.x * 256 + threadIdx.x, gsz = gridDim.x * 256;
  float v = 0.f;
  for (int e = tid; e < E0; e += gsz) {
    int s = src0[e], d = dst0[e];
    atomicAdd(&degi[d], 1);
    float r0 = pos0[s*3]   - pos0[d*3];
    float r1 = pos0[s*3+1] - pos0[d*3+1];
    float r2 = pos0[s*3+2] - pos0[d*3+2];
    erec0u[e] = make_int4(__float_as_int(x0[s]), __float_as_int(r0),
                          __float_as_int(r1), __float_as_int(r2));
    v = fmaxf(v, fmaxf(fabsf(r0), fmaxf(fabsf(r1), fabsf(r2))));
  }
  #pragma unroll
  for (int off = 32; off; off >>= 1) v = fmaxf(v, __shfl_down(v, off, 64));
  if ((threadIdx.x & 63) == 0) red[threadIdx.x >> 6] = v;
  __syncthreads();
  if (threadIdx.x == 0)
    atomicMax((unsigned*)mbuf,
              __float_as_uint(fmaxf(fmaxf(red[0], red[1]), fmaxf(red[2], red[3]))));
  // weight prep (blocks 0..377)
  for (int b = blockIdx.x; b < 378; b += gridDim.x) {
    const float *W, *Wr; unsigned short *oh, *ol; int K, N, kt, nt;
    if (b < 18)      { W = W2; Wr = Wr2; oh = w2h; ol = w2l; K = 576;  N = 128; kt = b / 2; nt = b % 2; }
    else if (b < 90) { int q = b - 18; W = W3; Wr = Wr3; oh = w3h; ol = w3l; K = 1152; N = 256; kt = q / 4; nt = q % 4; }
    else             { int q = b - 90; W = W4; Wr = Wr4; oh = w4h; ol = w4l; K = 2304; N = 512; kt = q / 8; nt = q % 8; }
    int k0 = kt * 64, n0 = nt * 64, KW = K - K / 9;
    __syncthreads();
    for (int i = threadIdx.x; i < 4096; i += 256) {
      int kk = i >> 6, nn = i & 63, k = k0 + kk;
      T[kk][nn] = (k < KW) ? W[(long)k * N + n0 + nn] : Wr[(long)(k - KW) * N + n0 + nn];
    }
    __syncthreads();
    for (int i = threadIdx.x; i < 4096; i += 256) {
      int nn = i >> 6, kk = i & 63;
      float vv = T[kk][nn];
      unsigned short hu = f2b(vv), lu = f2b(vv - b2f(hu));
      long o = (long)(n0 + nn) * K + k0 + kk;
      oh[o] = hu; ol[o] = lu;
    }
  }
  if (blockIdx.x == 0)
    for (int i = threadIdx.x; i < 576; i += 256)
      wc1[i] = (i < 512) ? W1[i] : Wr1[i - 512];
}

// ---------- k_alloc: bump-allocate CSR rows, clear degi ----------
__global__ void k_alloc(int* __restrict__ degi, int* __restrict__ rowbeg,
                        int* __restrict__ rowlen, int* __restrict__ cursor,
                        int* __restrict__ ctr, int N) {
  int n = blockIdx.x * 256 + threadIdx.x;
  if (n >= N) return;
  int len = degi[n];
  int st = atomicAdd(ctr, len);
  rowbeg[n] = st; cursor[n] = st; rowlen[n] = len; degi[n] = 0;
}

// ---------- k_scat: permute edge records into CSR order ----------
__global__ void k_scat(const int4* __restrict__ eu, const int* __restrict__ du,
                       const int* __restrict__ ecnt, int ecap,
                       int* __restrict__ cursor, int4* __restrict__ es) {
  int n = ecnt ? *ecnt : ecap;
  for (int e = blockIdx.x * 256 + threadIdx.x; e < n; e += gridDim.x * 256) {
    int p = atomicAdd(&cursor[du[e]], 1);
    es[p] = eu[e];
  }
}

// ---------- k_l1: two-phase fused layer-1 conv + pool-1 ----------
__global__ __launch_bounds__(256)
void k_l1(const float* __restrict__ pos0, const float* __restrict__ x0,
          const int4* __restrict__ erec, const int* __restrict__ rowbeg,
          const int* __restrict__ rowlen, const float* __restrict__ mbuf,
          const float* __restrict__ wc1, const float* __restrict__ b1,
          unsigned* __restrict__ pord1, float* __restrict__ cnt1,
          float* __restrict__ possum1, int* __restrict__ nid) {
  __shared__ float ys9[256][12];
  int t = threadIdx.x;
  int d = blockIdx.x * 256 + t;
  float inv = 0.5f / fmaxf(mbuf[0], 1e-9f);
  if (d < NL0) {
    int beg = rowbeg[d], len = rowlen[d];
    float acc[8] = {};
    for (int j = beg; j < beg + len; j++) {
      int4 rc = erec[j];
      float xv = __int_as_float(rc.x);
      float u0 = __int_as_float(rc.y) * inv + 0.5f;
      float u1 = __int_as_float(rc.z) * inv + 0.5f;
      float u2 = __int_as_float(rc.w) * inv + 0.5f;
      float w[8]; basis8(u0, u1, u2, w);
      #pragma unroll
      for (int k = 0; k < 8; k++) acc[k] += w[k] * xv;
    }
    float sc = 1.f / fmaxf((float)len, 1.f);
    #pragma unroll
    for (int k = 0; k < 8; k++) ys9[t][k] = acc[k] * sc;
    ys9[t][8]  = x0[d];
    ys9[t][9]  = pos0[d*3];
    ys9[t][10] = pos0[d*3+1];
    ys9[t][11] = pos0[d*3+2];
  }
  __syncthreads();
  int lane = t & 63, wv = t >> 6;
  float wcol[9];
  #pragma unroll
  for (int k = 0; k < 8; k++) wcol[k] = wc1[k * 64 + lane];
  wcol[8] = wc1[512 + lane];
  float bb = b1[lane];
  int base = blockIdx.x * 256 + wv * 64;
  for (int i = 0; i < 64; i++) {
    int dd = base + i;
    if (dd >= NL0) break;
    int li = wv * 64 + i;
    float v = bb + ys9[li][8] * wcol[8];
    #pragma unroll
    for (int k = 0; k < 8; k++) v += ys9[li][k] * wcol[k];
    v = eluf(v);
    float pd0 = ys9[li][9], pd1 = ys9[li][10], pd2 = ys9[li][11];
    int c0 = clampi((int)floorf(pd0 / 20.f), 0, 11);
    int c1 = clampi((int)floorf(pd1 / 20.f), 0, 11);
    int c2 = clampi((int)floorf(pd2 / 20.f), 0, 11);
    int id = (dd / 5000) * 1728 + (c0 * 12 + c1) * 12 + c2;
    atomicMax(&pord1[(long)id * 64 + lane], f2ord(v));
    if (lane == 0) {
      nid[dd] = id;
      atomicAdd(&cnt1[id], 1.f);
      atomicAdd(&possum1[id*3],   pd0);
      atomicAdd(&possum1[id*3+1], pd1);
      atomicAdd(&possum1[id*3+2], pd2);
    }
  }
}

// ---------- k_pedge: coarsen+dedup edges, emit records, count deg, absmax ----------
__global__ __launch_bounds__(256)
void k_pedge(const int4* __restrict__ erecf, const int* __restrict__ srcf,
             const int* __restrict__ dstf, const int* __restrict__ ecntf, int ecap,
             const int* __restrict__ nid, int Nn, unsigned* __restrict__ bitmap,
             int4* __restrict__ erecu, int* __restrict__ dstu, int* __restrict__ ecntc,
             int* __restrict__ degi, const float* __restrict__ possum,
             const float* __restrict__ cnt, float* __restrict__ mo) {
  __shared__ float red[4];
  int n = ecntf ? *ecntf : ecap;
  float vmax = 0.f;
  for (int e = blockIdx.x * 256 + threadIdx.x; e < n; e += gridDim.x * 256) {
    int sL = erecf ? erecf[e].x : srcf[e];
    int dL = dstf[e];
    int s2 = nid[sL], d2 = nid[dL];
    if (s2 == d2) continue;
    float ics = 1.f / fmaxf(cnt[s2], 1.f), icd = 1.f / fmaxf(cnt[d2], 1.f);
    float r0 = possum[s2*3]   * ics - possum[d2*3]   * icd;
    float r1 = possum[s2*3+1] * ics - possum[d2*3+1] * icd;
    float r2 = possum[s2*3+2] * ics - possum[d2*3+2] * icd;
    vmax = fmaxf(vmax, fmaxf(fabsf(r0), fmaxf(fabsf(r1), fabsf(r2))));
    unsigned key = (unsigned)s2 * (unsigned)Nn + (unsigned)d2;
    unsigned bit = 1u << (key & 31);
    unsigned old = atomicOr(&bitmap[key >> 5], bit);
    if (!(old & bit)) {
      int q = atomicAdd(ecntc, 1);
      erecu[q] = make_int4(s2, __float_as_int(r0), __float_as_int(r1), __float_as_int(r2));
      dstu[q] = d2;
      atomicAdd(&degi[d2], 1);
    }
  }
  #pragma unroll
  for (int off = 32; off; off >>= 1) vmax = fmaxf(vmax, __shfl_down(vmax, off, 64));
  if ((threadIdx.x & 63) == 0) red[threadIdx.x >> 6] = vmax;
  __syncthreads();
  if (threadIdx.x == 0)
    atomicMax((unsigned*)mo,
              __float_as_uint(fmaxf(fmaxf(red[0], red[1]), fmaxf(red[2], red[3]))));
}

// ---------- k_gather: CSR walk, packed records, emit bf16 hi/lo ----------
__global__ __launch_bounds__(256)
void k_gather(const unsigned* __restrict__ pordc, const int4* __restrict__ erec,
              const int* __restrict__ rowbeg, const int* __restrict__ rowlen,
              const float* __restrict__ mbuf,
              unsigned short* __restrict__ ysh, unsigned short* __restrict__ ysl,
              int N, int Ci, int nchunk) {
  int wid = blockIdx.x * 4 + (threadIdx.x >> 6);
  int lane = threadIdx.x & 63;
  int d = wid / nchunk, ch = wid % nchunk;
  if (d >= N) return;
  int co = ch * 64 + lane;
  float inv = 0.5f / fmaxf(mbuf[0], 1e-9f);
  int beg = rowbeg[d], len = rowlen[d], end = beg + len;
  float acc[8] = {};
  int j = beg;
  for (; j + 1 < end; j += 2) {
    int4 ra = erec[j], rb = erec[j + 1];
    float ua0 = __int_as_float(ra.y) * inv + 0.5f;
    float ua1 = __int_as_float(ra.z) * inv + 0.5f;
    float ua2 = __int_as_float(ra.w) * inv + 0.5f;
    float ub0 = __int_as_float(rb.y) * inv + 0.5f;
    float ub1 = __int_as_float(rb.z) * inv + 0.5f;
    float ub2 = __int_as_float(rb.w) * inv + 0.5f;
    float xa = ord2f(pordc[(long)ra.x * Ci + co]);
    float xb = ord2f(pordc[(long)rb.x * Ci + co]);
    float wa[8], wb[8];
    basis8(ua0, ua1, ua2, wa);
    basis8(ub0, ub1, ub2, wb);
    #pragma unroll
    for (int k = 0; k < 8; k++) acc[k] += wa[k] * xa + wb[k] * xb;
  }
  if (j < end) {
    int4 ra = erec[j];
    float ua0 = __int_as_float(ra.y) * inv + 0.5f;
    float ua1 = __int_as_float(ra.z) * inv + 0.5f;
    float ua2 = __int_as_float(ra.w) * inv + 0.5f;
    float xa = ord2f(pordc[(long)ra.x * Ci + co]);
    float wa[8];
    basis8(ua0, ua1, ua2, wa);
    #pragma unroll
    for (int k = 0; k < 8; k++) acc[k] += wa[k] * xa;
  }
  float sc = 1.f / fmaxf((float)len, 1.f);
  long row = (long)d * 9 * Ci;
  #pragma unroll
  for (int k = 0; k < 8; k++) {
    float v = acc[k] * sc;
    unsigned short hu = f2b(v);
    ysh[row + k * Ci + co] = hu;
    ysl[row + k * Ci + co] = f2b(v - b2f(hu));
  }
  float xd = ord2f(pordc[(long)d * Ci + co]);  // pord==0 (empty) decodes via cnt-gate below
  // empty dst cells have pord slot == 0 -> ord2f(0) = NaN-ish; but gather rows with
  // len==0 and empty dst only produce x-term; guard via ord==0 check:
  unsigned od = pordc[(long)d * Ci + co];
  xd = (od == 0u) ? 0.f : ord2f(od);
  unsigned short hu = f2b(xd);
  ysh[row + 8 * Ci + co] = hu;
  ysl[row + 8 * Ci + co] = f2b(xd - b2f(hu));
}

// ---------- k_gemmpool: MFMA GEMM + bias + ELU + voxel-pool epilogue ----------
__global__ __launch_bounds__(256)
void k_gemmpool(const unsigned short* __restrict__ ysh, const unsigned short* __restrict__ ysl,
                const unsigned short* __restrict__ Bh, const unsigned short* __restrict__ Bl,
                int M, int N, int K, const float* __restrict__ bias,
                const float* __restrict__ possum, const float* __restrict__ cnt,
                int div, float vs, int G, int NC,
                unsigned* __restrict__ pordn, float* __restrict__ cntn,
                float* __restrict__ possumn, int* __restrict__ nid) {
  __shared__ __align__(16) char smem[20480];
  int nbx = N >> 6;
  int bx = blockIdx.x % nbx, by = blockIdx.x / nbx;
  int m0 = by * 64, n0 = bx * 64;
  f32x4 acc[4] = {};
  mfma_tile(ysh, ysl, Bh, Bl, M, K, m0, n0, 0, K, smem, acc);
  int w = threadIdx.x >> 6, lane = threadIdx.x & 63;
  int row0 = m0 + (w << 4) + ((lane >> 4) << 2);
  int colb = n0 + (lane & 15);
  #pragma unroll
  for (int q = 0; q < 4; q++) {
    int gm = row0 + q;
    float c = cnt[gm];
    float ic = 1.f / fmaxf(c, 1.f);
    float p0 = possum[gm*3] * ic, p1 = possum[gm*3+1] * ic, p2 = possum[gm*3+2] * ic;
    int c0 = clampi((int)floorf(p0 / vs), 0, G - 1);
    int c1 = clampi((int)floorf(p1 / vs), 0, G - 1);
    int c2 = clampi((int)floorf(p2 / vs), 0, G - 1);
    int id = (gm / div) * NC + (c0 * G + c1) * G + c2;
    bool vl = c > 0.f;
    if (bx == 0 && (lane & 15) == 0) {
      nid[gm] = id;
      if (vl) {
        atomicAdd(&cntn[id], 1.f);
        atomicAdd(&possumn[id*3],   p0);
        atomicAdd(&possumn[id*3+1], p1);
        atomicAdd(&possumn[id*3+2], p2);
      }
    }
    if (vl) {
      #pragma unroll
      for (int nt = 0; nt < 4; nt++) {
        int col = colb + nt * 16;
        float v = eluf(acc[nt][q] + bias[col]);
        atomicMax(&pordn[(long)id * N + col], f2ord(v));
      }
    }
  }
}

// ---------- k_gemm4: layer-4 split-K z=4 partials ----------
__global__ __launch_bounds__(256)
void k_gemm4(const unsigned short* __restrict__ ysh, const unsigned short* __restrict__ ysl,
             const unsigned short* __restrict__ Bh, const unsigned short* __restrict__ Bl,
             float* __restrict__ Cp) {
  __shared__ __align__(16) char smem[20480];
  int z = blockIdx.x >> 6, rem = blockIdx.x & 63, bx = rem & 7, by = rem >> 3;
  int m0 = by * 64, n0 = bx * 64;
  f32x4 acc[4] = {};
  mfma_tile(ysh, ysl, Bh, Bl, 500, 2304, m0, n0, z * 576, 576, smem, acc);
  float* Co = Cp + (long)z * 256000;
  int w = threadIdx.x >> 6, lane = threadIdx.x & 63;
  int row0 = m0 + (w << 4) + ((lane >> 4) << 2);
  int colb = n0 + (lane & 15);
  #pragma unroll
  for (int nt = 0; nt < 4; nt++)
    #pragma unroll
    for (int q = 0; q < 4; q++) {
      int gm = row0 + q;
      if (gm < 500) Co[(long)gm * 512 + colb + nt * 16] = acc[nt][q];
    }
}

// ---------- k_reduce4: sum partials + bias + ELU + final MaxPoolingX ----------
__global__ void k_reduce4(const float* __restrict__ Cp, const float* __restrict__ b4,
                          const float* __restrict__ possum3, const float* __restrict__ cnt3,
                          unsigned* __restrict__ xg) {
  int idx = blockIdx.x * 256 + threadIdx.x;
  if (idx >= 256000) return;
  int n = idx >> 9, o = idx & 511;
  float s = Cp[idx] + Cp[idx + 256000] + Cp[idx + 512000] + Cp[idx + 768000];
  float v = eluf(s + b4[o]);
  float c = cnt3[n];
  if (c <= 0.f) return;
  float ic = 1.f / c;
  float p0 = possum3[n*3] * ic, p1 = possum3[n*3+1] * ic, p2 = possum3[n*3+2] * ic;
  int c0 = clampi((int)floorf(p0 / 80.f), 0, 2);
  int c1 = clampi((int)floorf(p1 / 80.f), 0, 2);
  int c2 = clampi((int)floorf(p2 / 80.f), 0, 2);
  int cl = (n / 125) * 64 + (c0 * 3 + c1) * 3 + c2;
  atomicMax(&xg[(long)cl * 512 + o], f2ord(v));
}

// ---------- FC1 (skips the 37/64 always-empty cells) ----------
__global__ __launch_bounds__(128)
void k_fc1(const unsigned* __restrict__ xg_ord, const float* __restrict__ w,
           float* __restrict__ h) {
  int cellhalf = blockIdx.x >> 3, jb = blockIdx.x & 7;
  int cell = cellhalf >> 1, half = cellhalf & 1;
  int j = jb * 128 + threadIdx.x;
  __shared__ float xs[4][256];
  for (int q = threadIdx.x; q < 1024; q += 128) {
    int b = q >> 8, ci = q & 255;
    unsigned o = xg_ord[((b * 64 + cell) << 9) + half * 256 + ci];
    xs[b][ci] = (o == 0u) ? 0.f : ord2f(o);
  }
  __syncthreads();
  float a0 = 0, a1 = 0, a2 = 0, a3 = 0;
  int cbase = cell * 512 + half * 256;
  for (int ci = 0; ci < 256; ci++) {
    float ww = w[(long)(cbase + ci) * 1024 + j];
    a0 += xs[0][ci] * ww; a1 += xs[1][ci] * ww;
    a2 += xs[2][ci] * ww; a3 += xs[3][ci] * ww;
  }
  atomicAdd(&h[j], a0);        atomicAdd(&h[1024 + j], a1);
  atomicAdd(&h[2048 + j], a2); atomicAdd(&h[3072 + j], a3);
}

// ---------- FC2 (fc1 bias+ELU fused) ----------
__global__ void k_fc2(const float* __restrict__ h, const float* __restrict__ fb1,
                      const float* __restrict__ w, const float* __restrict__ b,
                      float* __restrict__ out) {
  int bb = blockIdx.x, t = threadIdx.x;
  float a = 0;
  for (int j = t; j < 1024; j += 256) a += eluf(h[bb * 1024 + j] + fb1[j]) * w[j];
  for (int off = 32; off; off >>= 1) a += __shfl_down(a, off, 64);
  __shared__ float red[4];
  int lane = t & 63, wv = t >> 6;
  if (lane == 0) red[wv] = a;
  __syncthreads();
  if (t == 0) out[bb] = eluf(red[0] + red[1] + red[2] + red[3] + b[0]);
}

// =======================================================================
extern "C" void kernel_launch(void* const* d_in, const int* in_sizes, int n_in,
                              void* d_out, int out_size, void* d_ws, size_t ws_size,
                              hipStream_t stream) {
  const float* x0   = (const float*)d_in[0];
  const float* pos0 = (const float*)d_in[1];
  const int*   ei   = (const int*)d_in[2];
  const float* W1 = (const float*)d_in[4],  *Wr1 = (const float*)d_in[5],  *b1 = (const float*)d_in[6];
  const float* W2 = (const float*)d_in[7],  *Wr2 = (const float*)d_in[8],  *b2 = (const float*)d_in[9];
  const float* W3 = (const float*)d_in[10], *Wr3 = (const float*)d_in[11], *b3 = (const float*)d_in[12];
  const float* W4 = (const float*)d_in[13], *Wr4 = (const float*)d_in[14], *b4 = (const float*)d_in[15];
  const float* fw1 = (const float*)d_in[16], *fb1 = (const float*)d_in[17];
  const float* fw2 = (const float*)d_in[18], *fb2 = (const float*)d_in[19];
  float* out = (float*)d_out;
  const int* src0 = ei;
  const int* dst0 = ei + E0;

  char* ws = (char*)d_ws;
  size_t off = 0;
  auto alloc = [&](size_t bytes) -> void* {
    off = (off + 255) & ~(size_t)255;
    void* q = ws + off; off += bytes; return q;
  };
  // non-zeroed buffers
  int4* erec0u = (int4*)alloc((size_t)E0 * 16);
  int4* erec_s = (int4*)alloc((size_t)E0 * 16);     // sorted CSR records (reused per level)
  int4* eu_a   = (int4*)alloc((size_t)E0 * 16);     // unsorted records, ping
  int4* eu_b   = (int4*)alloc((size_t)E0 * 16);     // unsorted records, pong
  int* du_a = (int*)alloc(E0 * 4);
  int* du_b = (int*)alloc(E0 * 4);
  int* nid  = (int*)alloc(NL0 * 4);
  int* rowbeg = (int*)alloc(NL0 * 4);
  int* rowlen = (int*)alloc(NL0 * 4);
  int* cursor = (int*)alloc(NL0 * 4);
  unsigned short* ysh = (unsigned short*)alloc((size_t)NL1 * 576 * 2);
  unsigned short* ysl = (unsigned short*)alloc((size_t)NL1 * 576 * 2);
  float* wc1 = (float*)alloc(576 * 4);
  unsigned short* w2h = (unsigned short*)alloc((size_t)576 * 128 * 2);
  unsigned short* w2l = (unsigned short*)alloc((size_t)576 * 128 * 2);
  unsigned short* w3h = (unsigned short*)alloc((size_t)1152 * 256 * 2);
  unsigned short* w3l = (unsigned short*)alloc((size_t)1152 * 256 * 2);
  unsigned short* w4h = (unsigned short*)alloc((size_t)2304 * 512 * 2);
  unsigned short* w4l = (unsigned short*)alloc((size_t)2304 * 512 * 2);
  float* Cp = (float*)alloc((size_t)4 * 256000 * 4);
  // zero region (single memset per call)
  char* z0 = (char*)alloc(0);
  unsigned* pord1 = (unsigned*)alloc((size_t)NL1 * 64 * 4);
  unsigned* pord2 = (unsigned*)alloc((size_t)NL2 * 128 * 4);
  unsigned* pord3 = (unsigned*)alloc((size_t)NL3 * 256 * 4);
  unsigned* xg    = (unsigned*)alloc((size_t)4 * 64 * 512 * 4);
  float* cnt1 = (float*)alloc(NL1 * 4);
  float* cnt2 = (float*)alloc(NL2 * 4);
  float* cnt3 = (float*)alloc(NL3 * 4);
  float* possum1 = (float*)alloc(NL1 * 12);
  float* possum2 = (float*)alloc(NL2 * 12);
  float* possum3 = (float*)alloc(NL3 * 12);
  size_t bm1w = ((size_t)NL1 * NL1 + 31) / 32;
  size_t bm2w = ((size_t)NL2 * NL2 + 31) / 32;
  size_t bm3w = ((size_t)NL3 * NL3 + 31) / 32;
  unsigned* bm1 = (unsigned*)alloc(bm1w * 4);
  unsigned* bm2 = (unsigned*)alloc(bm2w * 4);
  unsigned* bm3 = (unsigned*)alloc(bm3w * 4);
  int* degi = (int*)alloc(NL0 * 4);
  float* mbuf = (float*)alloc(64);
  int* ecnt = (int*)(mbuf + 8);
  int* ctr  = (int*)(mbuf + 12);
  float* h = (float*)alloc(4096 * 4);
  char* zend = (char*)alloc(0);
  size_t zbytes = (size_t)(zend - z0);
  (void)ws_size; (void)in_sizes; (void)n_in; (void)out_size;

  auto cdiv = [](long a, long b) { return (int)((a + b - 1) / b); };

  hipMemsetAsync(z0, 0, zbytes, stream);

  // L0: deg + absmax + edge records + weight prep
  k_prep<<<512, 256, 0, stream>>>(src0, dst0, pos0, x0, degi, erec0u, mbuf,
                                  W1, Wr1, wc1, W2, Wr2, W3, Wr3, W4, Wr4,
                                  w2h, w2l, w3h, w3l, w4h, w4l);
  k_alloc<<<cdiv(NL0, 256), 256, 0, stream>>>(degi, rowbeg, rowlen, cursor, ctr + 0, NL0);
  k_scat<<<512, 256, 0, stream>>>(erec0u, dst0, nullptr, E0, cursor, erec_s);
  // layer 1 + pool 1
  k_l1<<<cdiv(NL0, 256), 256, 0, stream>>>(pos0, x0, erec_s, rowbeg, rowlen, mbuf,
                                           wc1, b1, pord1, cnt1, possum1, nid);
  k_pedge<<<512, 256, 0, stream>>>(nullptr, src0, dst0, nullptr, E0, nid, NL1, bm1,
                                   eu_a, du_a, ecnt + 0, degi, possum1, cnt1, mbuf + 1);
  k_alloc<<<cdiv(NL1, 256), 256, 0, stream>>>(degi, rowbeg, rowlen, cursor, ctr + 1, NL1);
  k_scat<<<512, 256, 0, stream>>>(eu_a, du_a, ecnt + 0, E0, cursor, erec_s);
  // layer 2 + pool 2
  k_gather<<<cdiv(NL1, 4), 256, 0, stream>>>(pord1, erec_s, rowbeg, rowlen, mbuf + 1,
                                             ysh, ysl, NL1, 64, 1);
  k_gemmpool<<<(128 / 64) * (NL1 / 64), 256, 0, stream>>>(
      ysh, ysl, w2h, w2l, NL1, 128, 576, b2, possum1, cnt1,
      1728, 30.f, 8, 512, pord2, cnt2, possum2, nid);
  k_pedge<<<512, 256, 0, stream>>>(eu_a, nullptr, du_a, ecnt + 0, E0, nid, NL2, bm2,
                                   eu_b, du_b, ecnt + 1, degi, possum2, cnt2, mbuf + 2);
  k_alloc<<<cdiv(NL2, 256), 256, 0, stream>>>(degi, rowbeg, rowlen, cursor, ctr + 2, NL2);
  k_scat<<<512, 256, 0, stream>>>(eu_b, du_b, ecnt + 1, E0, cursor, erec_s);
  // layer 3 + pool 3
  k_gather<<<cdiv(NL2 * 2, 4), 256, 0, stream>>>(pord2, erec_s, rowbeg, rowlen, mbuf + 2,
                                                 ysh, ysl, NL2, 128, 2);
  k_gemmpool<<<(256 / 64) * (NL2 / 64), 256, 0, stream>>>(
      ysh, ysl, w3h, w3l, NL2, 256, 1152, b3, possum2, cnt2,
      512, 50.f, 5, 125, pord3, cnt3, possum3, nid);
  k_pedge<<<512, 256, 0, stream>>>(eu_b, nullptr, du_b, ecnt + 1, E0, nid, NL3, bm3,
                                   eu_a, du_a, ecnt + 2, degi, possum3, cnt3, mbuf + 3);
  k_alloc<<<cdiv(NL3, 256), 256, 0, stream>>>(degi, rowbeg, rowlen, cursor, ctr + 3, NL3);
  k_scat<<<512, 256, 0, stream>>>(eu_a, du_a, ecnt + 2, E0, cursor, erec_s);
  // layer 4 + final pool
  k_gather<<<cdiv(NL3 * 4, 4), 256, 0, stream>>>(pord3, erec_s, rowbeg, rowlen, mbuf + 3,
                                                 ysh, ysl, NL3, 256, 4);
  k_gemm4<<<256, 256, 0, stream>>>(ysh, ysl, w4h, w4l, Cp);
  k_reduce4<<<cdiv(256000, 256), 256, 0, stream>>>(Cp, b4, possum3, cnt3, xg);
  // FC head
  k_fc1<<<27 * 2 * 8, 128, 0, stream>>>(xg, fw1, h);
  k_fc2<<<4, 256, 0, stream>>>(h, fb1, fw2, fb2, out);
}

// Round 8
// 413.144 us; speedup vs baseline: 1.0631x; 1.0631x over previous
//
#include <hip/hip_runtime.h>

static constexpr int E0 = 160000;   // level-0 edges
static constexpr int NL0 = 20000;   // nodes level 0
static constexpr int NL1 = 6912;    // 4 * 12^3   (voxel 20)
static constexpr int NL2 = 2048;    // 4 * 8^3    (voxel 30)
static constexpr int NL3 = 500;     // 4 * 5^3    (voxel 50)

typedef short bf16x8 __attribute__((ext_vector_type(8)));
typedef float f32x4 __attribute__((ext_vector_type(4)));

// ---------- helpers ----------
__device__ __forceinline__ unsigned f2ord(float f) {
  unsigned u = __float_as_uint(f);
  return (u & 0x80000000u) ? ~u : (u | 0x80000000u);
}
__device__ __forceinline__ float ord2f(unsigned u) {
  unsigned v = (u & 0x80000000u) ? (u & 0x7fffffffu) : ~u;
  return __uint_as_float(v);
}
__device__ __forceinline__ float eluf(float x) { return x > 0.f ? x : expm1f(x); }
__device__ __forceinline__ void basis8(float u0, float u1, float u2, float* w) {
  float a0 = 1.f - u0, a1 = 1.f - u1, a2 = 1.f - u2;
  w[0] = a0*a1*a2; w[1] = a0*a1*u2; w[2] = a0*u1*a2; w[3] = a0*u1*u2;
  w[4] = u0*a1*a2; w[5] = u0*a1*u2; w[6] = u0*u1*a2; w[7] = u0*u1*u2;
}
__device__ __forceinline__ unsigned short f2b(float f) {  // fp32 -> bf16 RNE
  unsigned u = __float_as_uint(f);
  return (unsigned short)((u + 0x7fffu + ((u >> 16) & 1u)) >> 16);
}
__device__ __forceinline__ float b2f(unsigned short h) {
  return __uint_as_float(((unsigned)h) << 16);
}
__device__ __forceinline__ int clampi(int v, int lo, int hi) {
  return v < lo ? lo : (v > hi ? hi : v);
}

// ---------- MFMA 64x64 tile core (bf16 hi/lo 3-pass) ----------
__device__ __forceinline__ void mfma_tile(const unsigned short* __restrict__ Ah,
    const unsigned short* __restrict__ Al, const unsigned short* __restrict__ Bh,
    const unsigned short* __restrict__ Bl, int M, long K, int m0, int n0,
    int kbeg, int ksl, char* smem, f32x4* acc) {
  auto Ash = (unsigned short (*)[40])(smem);
  auto Asl = (unsigned short (*)[40])(smem + 5120);
  auto Bsh = (unsigned short (*)[40])(smem + 10240);
  auto Bsl = (unsigned short (*)[40])(smem + 15360);
  int t = threadIdx.x;
  int r = t >> 2, sg = (t & 3) * 8;
  int w = t >> 6, lane = t & 63;
  int ar = (w << 4) + (lane & 15), kq = (lane >> 4) << 3;
  for (int kt = 0; kt < ksl; kt += 32) {
    bf16x8 va = {}, vl = {};
    if (m0 + r < M) {
      long ga = (long)(m0 + r) * K + kbeg + kt + sg;
      va = *(const bf16x8*)&Ah[ga];
      vl = *(const bf16x8*)&Al[ga];
    }
    *(bf16x8*)&Ash[r][sg] = va;
    *(bf16x8*)&Asl[r][sg] = vl;
    long gb = (long)(n0 + r) * K + kbeg + kt + sg;
    *(bf16x8*)&Bsh[r][sg] = *(const bf16x8*)&Bh[gb];
    *(bf16x8*)&Bsl[r][sg] = *(const bf16x8*)&Bl[gb];
    __syncthreads();
    bf16x8 ah = *(const bf16x8*)&Ash[ar][kq];
    bf16x8 al = *(const bf16x8*)&Asl[ar][kq];
    #pragma unroll
    for (int nt = 0; nt < 4; nt++) {
      int br = (nt << 4) + (lane & 15);
      bf16x8 bh = *(const bf16x8*)&Bsh[br][kq];
      bf16x8 bl = *(const bf16x8*)&Bsl[br][kq];
      acc[nt] = __builtin_amdgcn_mfma_f32_16x16x32_bf16(al, bh, acc[nt], 0, 0, 0);
      acc[nt] = __builtin_amdgcn_mfma_f32_16x16x32_bf16(ah, bl, acc[nt], 0, 0, 0);
      acc[nt] = __builtin_amdgcn_mfma_f32_16x16x32_bf16(ah, bh, acc[nt], 0, 0, 0);
    }
    __syncthreads();
  }
}

// ---------- k_prep: L0 deg count + absmax + edge records + weight prep ----------
__global__ __launch_bounds__(256)
void k_prep(const int* __restrict__ src0, const int* __restrict__ dst0,
            const float* __restrict__ pos0, const float* __restrict__ x0,
            int* __restrict__ degi, int4* __restrict__ erec0u, float* __restrict__ mbuf,
            const float* __restrict__ W1, const float* __restrict__ Wr1, float* __restrict__ wc1,
            const float* __restrict__ W2, const float* __restrict__ Wr2,
            const float* __restrict__ W3, const float* __restrict__ Wr3,
            const float* __restrict__ W4, const float* __restrict__ Wr4,
            unsigned short* __restrict__ w2h, unsigned short* __restrict__ w2l,
            unsigned short* __restrict__ w3h, unsigned short* __restrict__ w3l,
            unsigned short* __restrict__ w4h, unsigned short* __restrict__ w4l) {
  __shared__ __align__(16) float T[64][65];
  __shared__ float red[4];
  int tid = blockIdx.x * 256 + threadIdx.x, gsz = gridDim.x * 256;
  float v = 0.f;
  for (int e = tid; e < E0; e += gsz) {
    int s = src0[e], d = dst0[e];
    atomicAdd(&degi[d], 1);
    float r0 = pos0[s*3]   - pos0[d*3];
    float r1 = pos0[s*3+1] - pos0[d*3+1];
    float r2 = pos0[s*3+2] - pos0[d*3+2];
    erec0u[e] = make_int4(__float_as_int(x0[s]), __float_as_int(r0),
                          __float_as_int(r1), __float_as_int(r2));
    v = fmaxf(v, fmaxf(fabsf(r0), fmaxf(fabsf(r1), fabsf(r2))));
  }
  #pragma unroll
  for (int off = 32; off; off >>= 1) v = fmaxf(v, __shfl_down(v, off, 64));
  if ((threadIdx.x & 63) == 0) red[threadIdx.x >> 6] = v;
  __syncthreads();
  if (threadIdx.x == 0)
    atomicMax((unsigned*)mbuf,
              __float_as_uint(fmaxf(fmaxf(red[0], red[1]), fmaxf(red[2], red[3]))));
  // weight prep (blocks 0..377)
  for (int b = blockIdx.x; b < 378; b += gridDim.x) {
    const float *W, *Wr; unsigned short *oh, *ol; int K, N, kt, nt;
    if (b < 18)      { W = W2; Wr = Wr2; oh = w2h; ol = w2l; K = 576;  N = 128; kt = b / 2; nt = b % 2; }
    else if (b < 90) { int q = b - 18; W = W3; Wr = Wr3; oh = w3h; ol = w3l; K = 1152; N = 256; kt = q / 4; nt = q % 4; }
    else             { int q = b - 90; W = W4; Wr = Wr4; oh = w4h; ol = w4l; K = 2304; N = 512; kt = q / 8; nt = q % 8; }
    int k0 = kt * 64, n0 = nt * 64, KW = K - K / 9;
    __syncthreads();
    for (int i = threadIdx.x; i < 4096; i += 256) {
      int kk = i >> 6, nn = i & 63, k = k0 + kk;
      T[kk][nn] = (k < KW) ? W[(long)k * N + n0 + nn] : Wr[(long)(k - KW) * N + n0 + nn];
    }
    __syncthreads();
    for (int i = threadIdx.x; i < 4096; i += 256) {
      int nn = i >> 6, kk = i & 63;
      float vv = T[kk][nn];
      unsigned short hu = f2b(vv), lu = f2b(vv - b2f(hu));
      long o = (long)(n0 + nn) * K + k0 + kk;
      oh[o] = hu; ol[o] = lu;
    }
  }
  if (blockIdx.x == 0)
    for (int i = threadIdx.x; i < 576; i += 256)
      wc1[i] = (i < 512) ? W1[i] : Wr1[i - 512];
}

// ---------- k_alloc: bump-allocate CSR rows, clear degi ----------
__global__ void k_alloc(int* __restrict__ degi, int* __restrict__ rowbeg,
                        int* __restrict__ rowlen, int* __restrict__ cursor,
                        int* __restrict__ ctr, int N) {
  int n = blockIdx.x * 256 + threadIdx.x;
  if (n >= N) return;
  int len = degi[n];
  int st = atomicAdd(ctr, len);
  rowbeg[n] = st; cursor[n] = st; rowlen[n] = len; degi[n] = 0;
}

// ---------- k_scat: permute edge records into CSR order ----------
__global__ void k_scat(const int4* __restrict__ eu, const int* __restrict__ du,
                       const int* __restrict__ ecnt, int ecap,
                       int* __restrict__ cursor, int4* __restrict__ es) {
  int n = ecnt ? *ecnt : ecap;
  for (int e = blockIdx.x * 256 + threadIdx.x; e < n; e += gridDim.x * 256) {
    int p = atomicAdd(&cursor[du[e]], 1);
    es[p] = eu[e];
  }
}

// ---------- k_l1: two-phase fused layer-1 conv + pool-1 ----------
__global__ __launch_bounds__(256)
void k_l1(const float* __restrict__ pos0, const float* __restrict__ x0,
          const int4* __restrict__ erec, const int* __restrict__ rowbeg,
          const int* __restrict__ rowlen, const float* __restrict__ mbuf,
          const float* __restrict__ wc1, const float* __restrict__ b1,
          unsigned* __restrict__ pord1, float* __restrict__ cnt1,
          float* __restrict__ possum1, int* __restrict__ nid) {
  __shared__ float ys9[256][12];
  int t = threadIdx.x;
  int d = blockIdx.x * 256 + t;
  float inv = 0.5f / fmaxf(mbuf[0], 1e-9f);
  if (d < NL0) {
    int beg = rowbeg[d], len = rowlen[d];
    float acc[8] = {};
    for (int j = beg; j < beg + len; j++) {
      int4 rc = erec[j];
      float xv = __int_as_float(rc.x);
      float u0 = __int_as_float(rc.y) * inv + 0.5f;
      float u1 = __int_as_float(rc.z) * inv + 0.5f;
      float u2 = __int_as_float(rc.w) * inv + 0.5f;
      float w[8]; basis8(u0, u1, u2, w);
      #pragma unroll
      for (int k = 0; k < 8; k++) acc[k] += w[k] * xv;
    }
    float sc = 1.f / fmaxf((float)len, 1.f);
    #pragma unroll
    for (int k = 0; k < 8; k++) ys9[t][k] = acc[k] * sc;
    ys9[t][8]  = x0[d];
    ys9[t][9]  = pos0[d*3];
    ys9[t][10] = pos0[d*3+1];
    ys9[t][11] = pos0[d*3+2];
  }
  __syncthreads();
  int lane = t & 63, wv = t >> 6;
  float wcol[9];
  #pragma unroll
  for (int k = 0; k < 8; k++) wcol[k] = wc1[k * 64 + lane];
  wcol[8] = wc1[512 + lane];
  float bb = b1[lane];
  int base = blockIdx.x * 256 + wv * 64;
  for (int i = 0; i < 64; i++) {
    int dd = base + i;
    if (dd >= NL0) break;
    int li = wv * 64 + i;
    float v = bb + ys9[li][8] * wcol[8];
    #pragma unroll
    for (int k = 0; k < 8; k++) v += ys9[li][k] * wcol[k];
    v = eluf(v);
    float pd0 = ys9[li][9], pd1 = ys9[li][10], pd2 = ys9[li][11];
    int c0 = clampi((int)floorf(pd0 / 20.f), 0, 11);
    int c1 = clampi((int)floorf(pd1 / 20.f), 0, 11);
    int c2 = clampi((int)floorf(pd2 / 20.f), 0, 11);
    int id = (dd / 5000) * 1728 + (c0 * 12 + c1) * 12 + c2;
    atomicMax(&pord1[(long)id * 64 + lane], f2ord(v));
    if (lane == 0) {
      nid[dd] = id;
      atomicAdd(&cnt1[id], 1.f);
      atomicAdd(&possum1[id*3],   pd0);
      atomicAdd(&possum1[id*3+1], pd1);
      atomicAdd(&possum1[id*3+2], pd2);
    }
  }
}

// ---------- k_pedge: coarsen+dedup, wave-aggregated compaction ----------
__global__ __launch_bounds__(256)
void k_pedge(const int4* __restrict__ erecf, const int* __restrict__ srcf,
             const int* __restrict__ dstf, const int* __restrict__ ecntf, int ecap,
             const int* __restrict__ nid, int Nn, unsigned* __restrict__ bitmap,
             int4* __restrict__ erecu, int* __restrict__ dstu, int* __restrict__ ecntc,
             int* __restrict__ degi, const float* __restrict__ possum,
             const float* __restrict__ cnt, float* __restrict__ mo) {
  __shared__ float red[4];
  int n = ecntf ? *ecntf : ecap;
  int lane = threadIdx.x & 63;
  int stride = gridDim.x * 256;
  float vmax = 0.f;
  for (int base = blockIdx.x * 256; base < n; base += stride) {
    int e = base + threadIdx.x;
    bool win = false;
    int s2 = 0, d2 = 0;
    float r0 = 0.f, r1 = 0.f, r2 = 0.f;
    if (e < n) {
      int sL = erecf ? erecf[e].x : srcf[e];
      int dL = dstf[e];
      s2 = nid[sL]; d2 = nid[dL];
      if (s2 != d2) {
        float ics = 1.f / fmaxf(cnt[s2], 1.f), icd = 1.f / fmaxf(cnt[d2], 1.f);
        r0 = possum[s2*3]   * ics - possum[d2*3]   * icd;
        r1 = possum[s2*3+1] * ics - possum[d2*3+1] * icd;
        r2 = possum[s2*3+2] * ics - possum[d2*3+2] * icd;
        vmax = fmaxf(vmax, fmaxf(fabsf(r0), fmaxf(fabsf(r1), fabsf(r2))));
        unsigned key = (unsigned)s2 * (unsigned)Nn + (unsigned)d2;
        unsigned bit = 1u << (key & 31);
        unsigned old = atomicOr(&bitmap[key >> 5], bit);
        win = !(old & bit);
      }
    }
    unsigned long long mask = __ballot(win);
    if (mask) {
      int leader = __ffsll((unsigned long long)mask) - 1;
      int bq = 0;
      if (lane == leader) bq = atomicAdd(ecntc, __popcll(mask));
      bq = __shfl(bq, leader, 64);
      if (win) {
        int q = bq + __popcll(mask & ((1ULL << lane) - 1ULL));
        erecu[q] = make_int4(s2, __float_as_int(r0), __float_as_int(r1), __float_as_int(r2));
        dstu[q] = d2;
        atomicAdd(&degi[d2], 1);
      }
    }
  }
  #pragma unroll
  for (int off = 32; off; off >>= 1) vmax = fmaxf(vmax, __shfl_down(vmax, off, 64));
  if ((threadIdx.x & 63) == 0) red[threadIdx.x >> 6] = vmax;
  __syncthreads();
  if (threadIdx.x == 0)
    atomicMax((unsigned*)mo,
              __float_as_uint(fmaxf(fmaxf(red[0], red[1]), fmaxf(red[2], red[3]))));
}

// ---------- k_gather: CSR walk, unroll x4, ESPLIT waves/row, emit bf16 hi/lo ----------
template<int ES>
__global__ __launch_bounds__(256)
void k_gather(const unsigned* __restrict__ pordc, const int4* __restrict__ erec,
              const int* __restrict__ rowbeg, const int* __restrict__ rowlen,
              const float* __restrict__ mbuf,
              unsigned short* __restrict__ ysh, unsigned short* __restrict__ ysl,
              int N, int Ci, int nchunk) {
  __shared__ float comb[4][64][8];
  int wv = threadIdx.x >> 6, lane = threadIdx.x & 63;
  int gw = blockIdx.x * 4 + wv;
  int job = gw / ES, sub = gw % ES;
  int d = job / nchunk, ch = job % nchunk;
  bool active = d < N;
  float inv = 0.5f / fmaxf(mbuf[0], 1e-9f);
  int co = ch * 64 + lane;
  float acc[8] = {};
  int beg = 0, len = 0;
  if (active) {
    beg = rowbeg[d]; len = rowlen[d];
    int end = beg + len;
    int j = beg + sub;
    for (; j + 3 * ES < end; j += 4 * ES) {
      int4 ra = erec[j], rb = erec[j + ES], rc = erec[j + 2 * ES], rd = erec[j + 3 * ES];
      float xa = ord2f(pordc[(long)ra.x * Ci + co]);
      float xb = ord2f(pordc[(long)rb.x * Ci + co]);
      float xc = ord2f(pordc[(long)rc.x * Ci + co]);
      float xd = ord2f(pordc[(long)rd.x * Ci + co]);
      float wa[8], wb[8], wc[8], wd[8];
      basis8(__int_as_float(ra.y) * inv + 0.5f, __int_as_float(ra.z) * inv + 0.5f,
             __int_as_float(ra.w) * inv + 0.5f, wa);
      basis8(__int_as_float(rb.y) * inv + 0.5f, __int_as_float(rb.z) * inv + 0.5f,
             __int_as_float(rb.w) * inv + 0.5f, wb);
      basis8(__int_as_float(rc.y) * inv + 0.5f, __int_as_float(rc.z) * inv + 0.5f,
             __int_as_float(rc.w) * inv + 0.5f, wc);
      basis8(__int_as_float(rd.y) * inv + 0.5f, __int_as_float(rd.z) * inv + 0.5f,
             __int_as_float(rd.w) * inv + 0.5f, wd);
      #pragma unroll
      for (int k = 0; k < 8; k++)
        acc[k] += wa[k] * xa + wb[k] * xb + wc[k] * xc + wd[k] * xd;
    }
    for (; j < end; j += ES) {
      int4 ra = erec[j];
      float xa = ord2f(pordc[(long)ra.x * Ci + co]);
      float wa[8];
      basis8(__int_as_float(ra.y) * inv + 0.5f, __int_as_float(ra.z) * inv + 0.5f,
             __int_as_float(ra.w) * inv + 0.5f, wa);
      #pragma unroll
      for (int k = 0; k < 8; k++) acc[k] += wa[k] * xa;
    }
  }
  if (ES > 1) {
    #pragma unroll
    for (int k = 0; k < 8; k++) comb[wv][lane][k] = acc[k];
    __syncthreads();
    if (sub != 0 || !active) return;
    #pragma unroll
    for (int s = 1; s < ES; s++)
      #pragma unroll
      for (int k = 0; k < 8; k++) acc[k] += comb[wv + s][lane][k];
  } else if (!active) return;
  float sc = 1.f / fmaxf((float)len, 1.f);
  long row = (long)d * 9 * Ci;
  #pragma unroll
  for (int k = 0; k < 8; k++) {
    float v = acc[k] * sc;
    unsigned short hu = f2b(v);
    ysh[row + k * Ci + co] = hu;
    ysl[row + k * Ci + co] = f2b(v - b2f(hu));
  }
  unsigned od = pordc[(long)d * Ci + co];
  float xdv = (od == 0u) ? 0.f : ord2f(od);
  unsigned short hu = f2b(xdv);
  ysh[row + 8 * Ci + co] = hu;
  ysl[row + 8 * Ci + co] = f2b(xdv - b2f(hu));
}

// ---------- k_gemmpool: MFMA GEMM + bias + ELU + voxel-pool epilogue ----------
__global__ __launch_bounds__(256)
void k_gemmpool(const unsigned short* __restrict__ ysh, const unsigned short* __restrict__ ysl,
                const unsigned short* __restrict__ Bh, const unsigned short* __restrict__ Bl,
                int M, int N, int K, const float* __restrict__ bias,
                const float* __restrict__ possum, const float* __restrict__ cnt,
                int div, float vs, int G, int NC,
                unsigned* __restrict__ pordn, float* __restrict__ cntn,
                float* __restrict__ possumn, int* __restrict__ nid) {
  __shared__ __align__(16) char smem[20480];
  int nbx = N >> 6;
  int bx = blockIdx.x % nbx, by = blockIdx.x / nbx;
  int m0 = by * 64, n0 = bx * 64;
  f32x4 acc[4] = {};
  mfma_tile(ysh, ysl, Bh, Bl, M, K, m0, n0, 0, K, smem, acc);
  int w = threadIdx.x >> 6, lane = threadIdx.x & 63;
  int row0 = m0 + (w << 4) + ((lane >> 4) << 2);
  int colb = n0 + (lane & 15);
  #pragma unroll
  for (int q = 0; q < 4; q++) {
    int gm = row0 + q;
    float c = cnt[gm];
    float ic = 1.f / fmaxf(c, 1.f);
    float p0 = possum[gm*3] * ic, p1 = possum[gm*3+1] * ic, p2 = possum[gm*3+2] * ic;
    int c0 = clampi((int)floorf(p0 / vs), 0, G - 1);
    int c1 = clampi((int)floorf(p1 / vs), 0, G - 1);
    int c2 = clampi((int)floorf(p2 / vs), 0, G - 1);
    int id = (gm / div) * NC + (c0 * G + c1) * G + c2;
    bool vl = c > 0.f;
    if (bx == 0 && (lane & 15) == 0) {
      nid[gm] = id;
      if (vl) {
        atomicAdd(&cntn[id], 1.f);
        atomicAdd(&possumn[id*3],   p0);
        atomicAdd(&possumn[id*3+1], p1);
        atomicAdd(&possumn[id*3+2], p2);
      }
    }
    if (vl) {
      #pragma unroll
      for (int nt = 0; nt < 4; nt++) {
        int col = colb + nt * 16;
        float v = eluf(acc[nt][q] + bias[col]);
        atomicMax(&pordn[(long)id * N + col], f2ord(v));
      }
    }
  }
}

// ---------- k_gemm4: layer-4 split-K z=4 partials ----------
__global__ __launch_bounds__(256)
void k_gemm4(const unsigned short* __restrict__ ysh, const unsigned short* __restrict__ ysl,
             const unsigned short* __restrict__ Bh, const unsigned short* __restrict__ Bl,
             float* __restrict__ Cp) {
  __shared__ __align__(16) char smem[20480];
  int z = blockIdx.x >> 6, rem = blockIdx.x & 63, bx = rem & 7, by = rem >> 3;
  int m0 = by * 64, n0 = bx * 64;
  f32x4 acc[4] = {};
  mfma_tile(ysh, ysl, Bh, Bl, 500, 2304, m0, n0, z * 576, 576, smem, acc);
  float* Co = Cp + (long)z * 256000;
  int w = threadIdx.x >> 6, lane = threadIdx.x & 63;
  int row0 = m0 + (w << 4) + ((lane >> 4) << 2);
  int colb = n0 + (lane & 15);
  #pragma unroll
  for (int nt = 0; nt < 4; nt++)
    #pragma unroll
    for (int q = 0; q < 4; q++) {
      int gm = row0 + q;
      if (gm < 500) Co[(long)gm * 512 + colb + nt * 16] = acc[nt][q];
    }
}

// ---------- k_reduce4: sum partials + bias + ELU + final MaxPoolingX ----------
__global__ void k_reduce4(const float* __restrict__ Cp, const float* __restrict__ b4,
                          const float* __restrict__ possum3, const float* __restrict__ cnt3,
                          unsigned* __restrict__ xg) {
  int idx = blockIdx.x * 256 + threadIdx.x;
  if (idx >= 256000) return;
  int n = idx >> 9, o = idx & 511;
  float s = Cp[idx] + Cp[idx + 256000] + Cp[idx + 512000] + Cp[idx + 768000];
  float v = eluf(s + b4[o]);
  float c = cnt3[n];
  if (c <= 0.f) return;
  float ic = 1.f / c;
  float p0 = possum3[n*3] * ic, p1 = possum3[n*3+1] * ic, p2 = possum3[n*3+2] * ic;
  int c0 = clampi((int)floorf(p0 / 80.f), 0, 2);
  int c1 = clampi((int)floorf(p1 / 80.f), 0, 2);
  int c2 = clampi((int)floorf(p2 / 80.f), 0, 2);
  int cl = (n / 125) * 64 + (c0 * 3 + c1) * 3 + c2;
  atomicMax(&xg[(long)cl * 512 + o], f2ord(v));
}

// ---------- FC1 (skips the 37/64 always-empty cells) ----------
__global__ __launch_bounds__(128)
void k_fc1(const unsigned* __restrict__ xg_ord, const float* __restrict__ w,
           float* __restrict__ h) {
  int cellhalf = blockIdx.x >> 3, jb = blockIdx.x & 7;
  int cell = cellhalf >> 1, half = cellhalf & 1;
  int j = jb * 128 + threadIdx.x;
  __shared__ float xs[4][256];
  for (int q = threadIdx.x; q < 1024; q += 128) {
    int b = q >> 8, ci = q & 255;
    unsigned o = xg_ord[((b * 64 + cell) << 9) + half * 256 + ci];
    xs[b][ci] = (o == 0u) ? 0.f : ord2f(o);
  }
  __syncthreads();
  float a0 = 0, a1 = 0, a2 = 0, a3 = 0;
  int cbase = cell * 512 + half * 256;
  for (int ci = 0; ci < 256; ci++) {
    float ww = w[(long)(cbase + ci) * 1024 + j];
    a0 += xs[0][ci] * ww; a1 += xs[1][ci] * ww;
    a2 += xs[2][ci] * ww; a3 += xs[3][ci] * ww;
  }
  atomicAdd(&h[j], a0);        atomicAdd(&h[1024 + j], a1);
  atomicAdd(&h[2048 + j], a2); atomicAdd(&h[3072 + j], a3);
}

// ---------- FC2 (fc1 bias+ELU fused) ----------
__global__ void k_fc2(const float* __restrict__ h, const float* __restrict__ fb1,
                      const float* __restrict__ w, const float* __restrict__ b,
                      float* __restrict__ out) {
  int bb = blockIdx.x, t = threadIdx.x;
  float a = 0;
  for (int j = t; j < 1024; j += 256) a += eluf(h[bb * 1024 + j] + fb1[j]) * w[j];
  for (int off = 32; off; off >>= 1) a += __shfl_down(a, off, 64);
  __shared__ float red[4];
  int lane = t & 63, wv = t >> 6;
  if (lane == 0) red[wv] = a;
  __syncthreads();
  if (t == 0) out[bb] = eluf(red[0] + red[1] + red[2] + red[3] + b[0]);
}

// =======================================================================
extern "C" void kernel_launch(void* const* d_in, const int* in_sizes, int n_in,
                              void* d_out, int out_size, void* d_ws, size_t ws_size,
                              hipStream_t stream) {
  const float* x0   = (const float*)d_in[0];
  const float* pos0 = (const float*)d_in[1];
  const int*   ei   = (const int*)d_in[2];
  const float* W1 = (const float*)d_in[4],  *Wr1 = (const float*)d_in[5],  *b1 = (const float*)d_in[6];
  const float* W2 = (const float*)d_in[7],  *Wr2 = (const float*)d_in[8],  *b2 = (const float*)d_in[9];
  const float* W3 = (const float*)d_in[10], *Wr3 = (const float*)d_in[11], *b3 = (const float*)d_in[12];
  const float* W4 = (const float*)d_in[13], *Wr4 = (const float*)d_in[14], *b4 = (const float*)d_in[15];
  const float* fw1 = (const float*)d_in[16], *fb1 = (const float*)d_in[17];
  const float* fw2 = (const float*)d_in[18], *fb2 = (const float*)d_in[19];
  float* out = (float*)d_out;
  const int* src0 = ei;
  const int* dst0 = ei + E0;

  char* ws = (char*)d_ws;
  size_t off = 0;
  auto alloc = [&](size_t bytes) -> void* {
    off = (off + 255) & ~(size_t)255;
    void* q = ws + off; off += bytes; return q;
  };
  // non-zeroed buffers
  int4* erec0u = (int4*)alloc((size_t)E0 * 16);
  int4* erec_s = (int4*)alloc((size_t)E0 * 16);
  int4* eu_a   = (int4*)alloc((size_t)E0 * 16);
  int4* eu_b   = (int4*)alloc((size_t)E0 * 16);
  int* du_a = (int*)alloc(E0 * 4);
  int* du_b = (int*)alloc(E0 * 4);
  int* nid  = (int*)alloc(NL0 * 4);
  int* rowbeg = (int*)alloc(NL0 * 4);
  int* rowlen = (int*)alloc(NL0 * 4);
  int* cursor = (int*)alloc(NL0 * 4);
  unsigned short* ysh = (unsigned short*)alloc((size_t)NL1 * 576 * 2);
  unsigned short* ysl = (unsigned short*)alloc((size_t)NL1 * 576 * 2);
  float* wc1 = (float*)alloc(576 * 4);
  unsigned short* w2h = (unsigned short*)alloc((size_t)576 * 128 * 2);
  unsigned short* w2l = (unsigned short*)alloc((size_t)576 * 128 * 2);
  unsigned short* w3h = (unsigned short*)alloc((size_t)1152 * 256 * 2);
  unsigned short* w3l = (unsigned short*)alloc((size_t)1152 * 256 * 2);
  unsigned short* w4h = (unsigned short*)alloc((size_t)2304 * 512 * 2);
  unsigned short* w4l = (unsigned short*)alloc((size_t)2304 * 512 * 2);
  float* Cp = (float*)alloc((size_t)4 * 256000 * 4);
  // zero region (single memset per call)
  char* z0 = (char*)alloc(0);
  unsigned* pord1 = (unsigned*)alloc((size_t)NL1 * 64 * 4);
  unsigned* pord2 = (unsigned*)alloc((size_t)NL2 * 128 * 4);
  unsigned* pord3 = (unsigned*)alloc((size_t)NL3 * 256 * 4);
  unsigned* xg    = (unsigned*)alloc((size_t)4 * 64 * 512 * 4);
  float* cnt1 = (float*)alloc(NL1 * 4);
  float* cnt2 = (float*)alloc(NL2 * 4);
  float* cnt3 = (float*)alloc(NL3 * 4);
  float* possum1 = (float*)alloc(NL1 * 12);
  float* possum2 = (float*)alloc(NL2 * 12);
  float* possum3 = (float*)alloc(NL3 * 12);
  size_t bm1w = ((size_t)NL1 * NL1 + 31) / 32;
  size_t bm2w = ((size_t)NL2 * NL2 + 31) / 32;
  size_t bm3w = ((size_t)NL3 * NL3 + 31) / 32;
  unsigned* bm1 = (unsigned*)alloc(bm1w * 4);
  unsigned* bm2 = (unsigned*)alloc(bm2w * 4);
  unsigned* bm3 = (unsigned*)alloc(bm3w * 4);
  int* degi = (int*)alloc(NL0 * 4);
  float* mbuf = (float*)alloc(64);
  int* ecnt = (int*)(mbuf + 8);
  int* ctr  = (int*)(mbuf + 12);
  float* h = (float*)alloc(4096 * 4);
  char* zend = (char*)alloc(0);
  size_t zbytes = (size_t)(zend - z0);
  (void)ws_size; (void)in_sizes; (void)n_in; (void)out_size;

  auto cdiv = [](long a, long b) { return (int)((a + b - 1) / b); };

  hipMemsetAsync(z0, 0, zbytes, stream);

  // L0: deg + absmax + edge records + weight prep
  k_prep<<<512, 256, 0, stream>>>(src0, dst0, pos0, x0, degi, erec0u, mbuf,
                                  W1, Wr1, wc1, W2, Wr2, W3, Wr3, W4, Wr4,
                                  w2h, w2l, w3h, w3l, w4h, w4l);
  k_alloc<<<cdiv(NL0, 256), 256, 0, stream>>>(degi, rowbeg, rowlen, cursor, ctr + 0, NL0);
  k_scat<<<512, 256, 0, stream>>>(erec0u, dst0, nullptr, E0, cursor, erec_s);
  // layer 1 + pool 1
  k_l1<<<cdiv(NL0, 256), 256, 0, stream>>>(pos0, x0, erec_s, rowbeg, rowlen, mbuf,
                                           wc1, b1, pord1, cnt1, possum1, nid);
  k_pedge<<<512, 256, 0, stream>>>(nullptr, src0, dst0, nullptr, E0, nid, NL1, bm1,
                                   eu_a, du_a, ecnt + 0, degi, possum1, cnt1, mbuf + 1);
  k_alloc<<<cdiv(NL1, 256), 256, 0, stream>>>(degi, rowbeg, rowlen, cursor, ctr + 1, NL1);
  k_scat<<<512, 256, 0, stream>>>(eu_a, du_a, ecnt + 0, E0, cursor, erec_s);
  // layer 2 + pool 2   (gather: ES=1, 6912 jobs)
  k_gather<1><<<cdiv(NL1, 4), 256, 0, stream>>>(pord1, erec_s, rowbeg, rowlen, mbuf + 1,
                                                ysh, ysl, NL1, 64, 1);
  k_gemmpool<<<(128 / 64) * (NL1 / 64), 256, 0, stream>>>(
      ysh, ysl, w2h, w2l, NL1, 128, 576, b2, possum1, cnt1,
      1728, 30.f, 8, 512, pord2, cnt2, possum2, nid);
  k_pedge<<<512, 256, 0, stream>>>(eu_a, nullptr, du_a, ecnt + 0, E0, nid, NL2, bm2,
                                   eu_b, du_b, ecnt + 1, degi, possum2, cnt2, mbuf + 2);
  k_alloc<<<cdiv(NL2, 256), 256, 0, stream>>>(degi, rowbeg, rowlen, cursor, ctr + 2, NL2);
  k_scat<<<512, 256, 0, stream>>>(eu_b, du_b, ecnt + 1, E0, cursor, erec_s);
  // layer 3 + pool 3   (gather: ES=2, 4096 jobs -> 8192 waves)
  k_gather<2><<<cdiv(NL2 * 2 * 2, 4), 256, 0, stream>>>(pord2, erec_s, rowbeg, rowlen, mbuf + 2,
                                                        ysh, ysl, NL2, 128, 2);
  k_gemmpool<<<(256 / 64) * (NL2 / 64), 256, 0, stream>>>(
      ysh, ysl, w3h, w3l, NL2, 256, 1152, b3, possum2, cnt2,
      512, 50.f, 5, 125, pord3, cnt3, possum3, nid);
  k_pedge<<<512, 256, 0, stream>>>(eu_b, nullptr, du_b, ecnt + 1, E0, nid, NL3, bm3,
                                   eu_a, du_a, ecnt + 2, degi, possum3, cnt3, mbuf + 3);
  k_alloc<<<cdiv(NL3, 256), 256, 0, stream>>>(degi, rowbeg, rowlen, cursor, ctr + 3, NL3);
  k_scat<<<512, 256, 0, stream>>>(eu_a, du_a, ecnt + 2, E0, cursor, erec_s);
  // layer 4 + final pool   (gather: ES=4, 2000 jobs -> 8000 waves)
  k_gather<4><<<cdiv(NL3 * 4 * 4, 4), 256, 0, stream>>>(pord3, erec_s, rowbeg, rowlen, mbuf + 3,
                                                        ysh, ysl, NL3, 256, 4);
  k_gemm4<<<256, 256, 0, stream>>>(ysh, ysl, w4h, w4l, Cp);
  k_reduce4<<<cdiv(256000, 256), 256, 0, stream>>>(Cp, b4, possum3, cnt3, xg);
  // FC head
  k_fc1<<<27 * 2 * 8, 128, 0, stream>>>(xg, fw1, h);
  k_fc2<<<4, 256, 0, stream>>>(h, fb1, fw2, fb2, out);
}

// Round 9
// 411.987 us; speedup vs baseline: 1.0661x; 1.0028x over previous
//
#include <hip/hip_runtime.h>

static constexpr int E0 = 160000;   // level-0 edges
static constexpr int NL0 = 20000;   // nodes level 0
static constexpr int NL1 = 6912;    // 4 * 12^3   (voxel 20)
static constexpr int NL2 = 2048;    // 4 * 8^3    (voxel 30)
static constexpr int NL3 = 500;     // 4 * 5^3    (voxel 50)

typedef short bf16x8 __attribute__((ext_vector_type(8)));
typedef float f32x4 __attribute__((ext_vector_type(4)));

// ---------- helpers ----------
__device__ __forceinline__ unsigned f2ord(float f) {
  unsigned u = __float_as_uint(f);
  return (u & 0x80000000u) ? ~u : (u | 0x80000000u);
}
__device__ __forceinline__ float ord2f(unsigned u) {
  unsigned v = (u & 0x80000000u) ? (u & 0x7fffffffu) : ~u;
  return __uint_as_float(v);
}
__device__ __forceinline__ float eluf(float x) { return x > 0.f ? x : expm1f(x); }
__device__ __forceinline__ void basis8(float u0, float u1, float u2, float* w) {
  float a0 = 1.f - u0, a1 = 1.f - u1, a2 = 1.f - u2;
  w[0] = a0*a1*a2; w[1] = a0*a1*u2; w[2] = a0*u1*a2; w[3] = a0*u1*u2;
  w[4] = u0*a1*a2; w[5] = u0*a1*u2; w[6] = u0*u1*a2; w[7] = u0*u1*u2;
}
__device__ __forceinline__ unsigned short f2b(float f) {  // fp32 -> bf16 RNE
  unsigned u = __float_as_uint(f);
  return (unsigned short)((u + 0x7fffu + ((u >> 16) & 1u)) >> 16);
}
__device__ __forceinline__ float b2f(unsigned short h) {
  return __uint_as_float(((unsigned)h) << 16);
}
__device__ __forceinline__ int clampi(int v, int lo, int hi) {
  return v < lo ? lo : (v > hi ? hi : v);
}

// ---------- MFMA 64x64 tile core (bf16 hi/lo 3-pass) ----------
__device__ __forceinline__ void mfma_tile(const unsigned short* __restrict__ Ah,
    const unsigned short* __restrict__ Al, const unsigned short* __restrict__ Bh,
    const unsigned short* __restrict__ Bl, int M, long K, int m0, int n0,
    int kbeg, int ksl, char* smem, f32x4* acc) {
  auto Ash = (unsigned short (*)[40])(smem);
  auto Asl = (unsigned short (*)[40])(smem + 5120);
  auto Bsh = (unsigned short (*)[40])(smem + 10240);
  auto Bsl = (unsigned short (*)[40])(smem + 15360);
  int t = threadIdx.x;
  int r = t >> 2, sg = (t & 3) * 8;
  int w = t >> 6, lane = t & 63;
  int ar = (w << 4) + (lane & 15), kq = (lane >> 4) << 3;
  for (int kt = 0; kt < ksl; kt += 32) {
    bf16x8 va = {}, vl = {};
    if (m0 + r < M) {
      long ga = (long)(m0 + r) * K + kbeg + kt + sg;
      va = *(const bf16x8*)&Ah[ga];
      vl = *(const bf16x8*)&Al[ga];
    }
    *(bf16x8*)&Ash[r][sg] = va;
    *(bf16x8*)&Asl[r][sg] = vl;
    long gb = (long)(n0 + r) * K + kbeg + kt + sg;
    *(bf16x8*)&Bsh[r][sg] = *(const bf16x8*)&Bh[gb];
    *(bf16x8*)&Bsl[r][sg] = *(const bf16x8*)&Bl[gb];
    __syncthreads();
    bf16x8 ah = *(const bf16x8*)&Ash[ar][kq];
    bf16x8 al = *(const bf16x8*)&Asl[ar][kq];
    #pragma unroll
    for (int nt = 0; nt < 4; nt++) {
      int br = (nt << 4) + (lane & 15);
      bf16x8 bh = *(const bf16x8*)&Bsh[br][kq];
      bf16x8 bl = *(const bf16x8*)&Bsl[br][kq];
      acc[nt] = __builtin_amdgcn_mfma_f32_16x16x32_bf16(al, bh, acc[nt], 0, 0, 0);
      acc[nt] = __builtin_amdgcn_mfma_f32_16x16x32_bf16(ah, bl, acc[nt], 0, 0, 0);
      acc[nt] = __builtin_amdgcn_mfma_f32_16x16x32_bf16(ah, bh, acc[nt], 0, 0, 0);
    }
    __syncthreads();
  }
}

// ---------- k_prep: L0 deg count + absmax + edge records + weight prep ----------
__global__ __launch_bounds__(256)
void k_prep(const int* __restrict__ src0, const int* __restrict__ dst0,
            const float* __restrict__ pos0, const float* __restrict__ x0,
            int* __restrict__ degi, int4* __restrict__ erec0u, float* __restrict__ mbuf,
            const float* __restrict__ W1, const float* __restrict__ Wr1, float* __restrict__ wc1,
            const float* __restrict__ W2, const float* __restrict__ Wr2,
            const float* __restrict__ W3, const float* __restrict__ Wr3,
            const float* __restrict__ W4, const float* __restrict__ Wr4,
            unsigned short* __restrict__ w2h, unsigned short* __restrict__ w2l,
            unsigned short* __restrict__ w3h, unsigned short* __restrict__ w3l,
            unsigned short* __restrict__ w4h, unsigned short* __restrict__ w4l) {
  __shared__ __align__(16) float T[64][65];
  __shared__ float red[4];
  int tid = blockIdx.x * 256 + threadIdx.x, gsz = gridDim.x * 256;
  float v = 0.f;
  for (int e = tid; e < E0; e += gsz) {
    int s = src0[e], d = dst0[e];
    atomicAdd(&degi[d], 1);
    float r0 = pos0[s*3]   - pos0[d*3];
    float r1 = pos0[s*3+1] - pos0[d*3+1];
    float r2 = pos0[s*3+2] - pos0[d*3+2];
    erec0u[e] = make_int4(__float_as_int(x0[s]), __float_as_int(r0),
                          __float_as_int(r1), __float_as_int(r2));
    v = fmaxf(v, fmaxf(fabsf(r0), fmaxf(fabsf(r1), fabsf(r2))));
  }
  #pragma unroll
  for (int off = 32; off; off >>= 1) v = fmaxf(v, __shfl_down(v, off, 64));
  if ((threadIdx.x & 63) == 0) red[threadIdx.x >> 6] = v;
  __syncthreads();
  if (threadIdx.x == 0)
    atomicMax((unsigned*)mbuf,
              __float_as_uint(fmaxf(fmaxf(red[0], red[1]), fmaxf(red[2], red[3]))));
  // weight prep (blocks 0..377)
  for (int b = blockIdx.x; b < 378; b += gridDim.x) {
    const float *W, *Wr; unsigned short *oh, *ol; int K, N, kt, nt;
    if (b < 18)      { W = W2; Wr = Wr2; oh = w2h; ol = w2l; K = 576;  N = 128; kt = b / 2; nt = b % 2; }
    else if (b < 90) { int q = b - 18; W = W3; Wr = Wr3; oh = w3h; ol = w3l; K = 1152; N = 256; kt = q / 4; nt = q % 4; }
    else             { int q = b - 90; W = W4; Wr = Wr4; oh = w4h; ol = w4l; K = 2304; N = 512; kt = q / 8; nt = q % 8; }
    int k0 = kt * 64, n0 = nt * 64, KW = K - K / 9;
    __syncthreads();
    for (int i = threadIdx.x; i < 4096; i += 256) {
      int kk = i >> 6, nn = i & 63, k = k0 + kk;
      T[kk][nn] = (k < KW) ? W[(long)k * N + n0 + nn] : Wr[(long)(k - KW) * N + n0 + nn];
    }
    __syncthreads();
    for (int i = threadIdx.x; i < 4096; i += 256) {
      int nn = i >> 6, kk = i & 63;
      float vv = T[kk][nn];
      unsigned short hu = f2b(vv), lu = f2b(vv - b2f(hu));
      long o = (long)(n0 + nn) * K + k0 + kk;
      oh[o] = hu; ol[o] = lu;
    }
  }
  if (blockIdx.x == 0)
    for (int i = threadIdx.x; i < 576; i += 256)
      wc1[i] = (i < 512) ? W1[i] : Wr1[i - 512];
}

// ---------- k_alloc: bump-allocate CSR rows, clear degi ----------
__global__ void k_alloc(int* __restrict__ degi, int* __restrict__ rowbeg,
                        int* __restrict__ rowlen, int* __restrict__ cursor,
                        int* __restrict__ ctr, int N) {
  int n = blockIdx.x * 256 + threadIdx.x;
  if (n >= N) return;
  int len = degi[n];
  int st = atomicAdd(ctr, len);
  rowbeg[n] = st; cursor[n] = st; rowlen[n] = len; degi[n] = 0;
}

// ---------- k_scat: permute edge records into CSR order ----------
__global__ void k_scat(const int4* __restrict__ eu, const int* __restrict__ du,
                       const int* __restrict__ ecnt, int ecap,
                       int* __restrict__ cursor, int4* __restrict__ es) {
  int n = ecnt ? *ecnt : ecap;
  for (int e = blockIdx.x * 256 + threadIdx.x; e < n; e += gridDim.x * 256) {
    int p = atomicAdd(&cursor[du[e]], 1);
    es[p] = eu[e];
  }
}

// ---------- k_l1a: 8-lane-group per node, coalesced row walk -> ysg[20000][8] ----------
__global__ __launch_bounds__(256)
void k_l1a(const int4* __restrict__ erec, const int* __restrict__ rowbeg,
           const int* __restrict__ rowlen, const float* __restrict__ mbuf,
           float* __restrict__ ysg) {
  int t = threadIdx.x;
  int d = blockIdx.x * 32 + (t >> 3);
  if (d >= NL0) return;
  int sub = t & 7;
  float inv = 0.5f / fmaxf(mbuf[0], 1e-9f);
  int beg = rowbeg[d], len = rowlen[d], end = beg + len;
  float acc[8] = {};
  for (int j = beg + sub; j < end; j += 8) {
    int4 rc = erec[j];
    float xv = __int_as_float(rc.x);
    float w[8];
    basis8(__int_as_float(rc.y) * inv + 0.5f, __int_as_float(rc.z) * inv + 0.5f,
           __int_as_float(rc.w) * inv + 0.5f, w);
    #pragma unroll
    for (int k = 0; k < 8; k++) acc[k] += w[k] * xv;
  }
  #pragma unroll
  for (int m = 1; m < 8; m <<= 1)
    #pragma unroll
    for (int k = 0; k < 8; k++) acc[k] += __shfl_xor(acc[k], m, 64);
  if (sub == 0) {
    float sc = 1.f / fmaxf((float)len, 1.f);
    float4 o0 = make_float4(acc[0]*sc, acc[1]*sc, acc[2]*sc, acc[3]*sc);
    float4 o1 = make_float4(acc[4]*sc, acc[5]*sc, acc[6]*sc, acc[7]*sc);
    *(float4*)&ysg[d*8]     = o0;
    *(float4*)&ysg[d*8 + 4] = o1;
  }
}

// ---------- k_l1b: wave per node: matvec + bias + ELU + pool-1 atomics ----------
__global__ __launch_bounds__(256)
void k_l1b(const float* __restrict__ ysg, const float* __restrict__ x0,
           const float* __restrict__ pos0, const float* __restrict__ wc1,
           const float* __restrict__ b1,
           unsigned* __restrict__ pord1, float* __restrict__ cnt1,
           float* __restrict__ possum1, int* __restrict__ nid) {
  int wv = threadIdx.x >> 6, lane = threadIdx.x & 63;
  int d = blockIdx.x * 4 + wv;
  if (d >= NL0) return;
  float wcol[9];
  #pragma unroll
  for (int k = 0; k < 8; k++) wcol[k] = wc1[k * 64 + lane];
  wcol[8] = wc1[512 + lane];
  float4 a0 = *(const float4*)&ysg[d*8];
  float4 a1 = *(const float4*)&ysg[d*8 + 4];
  float v = b1[lane] + x0[d] * wcol[8]
          + a0.x * wcol[0] + a0.y * wcol[1] + a0.z * wcol[2] + a0.w * wcol[3]
          + a1.x * wcol[4] + a1.y * wcol[5] + a1.z * wcol[6] + a1.w * wcol[7];
  v = eluf(v);
  float pd0 = pos0[d*3], pd1 = pos0[d*3+1], pd2 = pos0[d*3+2];
  int c0 = clampi((int)floorf(pd0 / 20.f), 0, 11);
  int c1 = clampi((int)floorf(pd1 / 20.f), 0, 11);
  int c2 = clampi((int)floorf(pd2 / 20.f), 0, 11);
  int id = (d / 5000) * 1728 + (c0 * 12 + c1) * 12 + c2;
  atomicMax(&pord1[(long)id * 64 + lane], f2ord(v));
  if (lane == 0) {
    nid[d] = id;
    atomicAdd(&cnt1[id], 1.f);
    atomicAdd(&possum1[id*3],   pd0);
    atomicAdd(&possum1[id*3+1], pd1);
    atomicAdd(&possum1[id*3+2], pd2);
  }
}

// ---------- k_pedge: coarsen+dedup, wave-aggregated compaction ----------
__global__ __launch_bounds__(256)
void k_pedge(const int4* __restrict__ erecf, const int* __restrict__ srcf,
             const int* __restrict__ dstf, const int* __restrict__ ecntf, int ecap,
             const int* __restrict__ nid, int Nn, unsigned* __restrict__ bitmap,
             int4* __restrict__ erecu, int* __restrict__ dstu, int* __restrict__ ecntc,
             int* __restrict__ degi, const float* __restrict__ possum,
             const float* __restrict__ cnt, float* __restrict__ mo) {
  __shared__ float red[4];
  int n = ecntf ? *ecntf : ecap;
  int lane = threadIdx.x & 63;
  int stride = gridDim.x * 256;
  float vmax = 0.f;
  for (int base = blockIdx.x * 256; base < n; base += stride) {
    int e = base + threadIdx.x;
    bool win = false;
    int s2 = 0, d2 = 0;
    float r0 = 0.f, r1 = 0.f, r2 = 0.f;
    if (e < n) {
      int sL = erecf ? erecf[e].x : srcf[e];
      int dL = dstf[e];
      s2 = nid[sL]; d2 = nid[dL];
      if (s2 != d2) {
        float ics = 1.f / fmaxf(cnt[s2], 1.f), icd = 1.f / fmaxf(cnt[d2], 1.f);
        r0 = possum[s2*3]   * ics - possum[d2*3]   * icd;
        r1 = possum[s2*3+1] * ics - possum[d2*3+1] * icd;
        r2 = possum[s2*3+2] * ics - possum[d2*3+2] * icd;
        vmax = fmaxf(vmax, fmaxf(fabsf(r0), fmaxf(fabsf(r1), fabsf(r2))));
        unsigned key = (unsigned)s2 * (unsigned)Nn + (unsigned)d2;
        unsigned bit = 1u << (key & 31);
        unsigned old = atomicOr(&bitmap[key >> 5], bit);
        win = !(old & bit);
      }
    }
    unsigned long long mask = __ballot(win);
    if (mask) {
      int leader = __ffsll((unsigned long long)mask) - 1;
      int bq = 0;
      if (lane == leader) bq = atomicAdd(ecntc, __popcll(mask));
      bq = __shfl(bq, leader, 64);
      if (win) {
        int q = bq + __popcll(mask & ((1ULL << lane) - 1ULL));
        erecu[q] = make_int4(s2, __float_as_int(r0), __float_as_int(r1), __float_as_int(r2));
        dstu[q] = d2;
        atomicAdd(&degi[d2], 1);
      }
    }
  }
  #pragma unroll
  for (int off = 32; off; off >>= 1) vmax = fmaxf(vmax, __shfl_down(vmax, off, 64));
  if ((threadIdx.x & 63) == 0) red[threadIdx.x >> 6] = vmax;
  __syncthreads();
  if (threadIdx.x == 0)
    atomicMax((unsigned*)mo,
              __float_as_uint(fmaxf(fmaxf(red[0], red[1]), fmaxf(red[2], red[3]))));
}

// ---------- k_gather: CSR walk, unroll x4, ESPLIT waves/row, emit bf16 hi/lo ----------
template<int ES>
__global__ __launch_bounds__(256)
void k_gather(const unsigned* __restrict__ pordc, const int4* __restrict__ erec,
              const int* __restrict__ rowbeg, const int* __restrict__ rowlen,
              const float* __restrict__ mbuf,
              unsigned short* __restrict__ ysh, unsigned short* __restrict__ ysl,
              int N, int Ci, int nchunk) {
  __shared__ float comb[4][64][8];
  int wv = threadIdx.x >> 6, lane = threadIdx.x & 63;
  int gw = blockIdx.x * 4 + wv;
  int job = gw / ES, sub = gw % ES;
  int d = job / nchunk, ch = job % nchunk;
  bool active = d < N;
  float inv = 0.5f / fmaxf(mbuf[0], 1e-9f);
  int co = ch * 64 + lane;
  float acc[8] = {};
  int beg = 0, len = 0;
  if (active) {
    beg = rowbeg[d]; len = rowlen[d];
    int end = beg + len;
    int j = beg + sub;
    for (; j + 3 * ES < end; j += 4 * ES) {
      int4 ra = erec[j], rb = erec[j + ES], rc = erec[j + 2 * ES], rd = erec[j + 3 * ES];
      float xa = ord2f(pordc[(long)ra.x * Ci + co]);
      float xb = ord2f(pordc[(long)rb.x * Ci + co]);
      float xc = ord2f(pordc[(long)rc.x * Ci + co]);
      float xd = ord2f(pordc[(long)rd.x * Ci + co]);
      float wa[8], wb[8], wc[8], wd[8];
      basis8(__int_as_float(ra.y) * inv + 0.5f, __int_as_float(ra.z) * inv + 0.5f,
             __int_as_float(ra.w) * inv + 0.5f, wa);
      basis8(__int_as_float(rb.y) * inv + 0.5f, __int_as_float(rb.z) * inv + 0.5f,
             __int_as_float(rb.w) * inv + 0.5f, wb);
      basis8(__int_as_float(rc.y) * inv + 0.5f, __int_as_float(rc.z) * inv + 0.5f,
             __int_as_float(rc.w) * inv + 0.5f, wc);
      basis8(__int_as_float(rd.y) * inv + 0.5f, __int_as_float(rd.z) * inv + 0.5f,
             __int_as_float(rd.w) * inv + 0.5f, wd);
      #pragma unroll
      for (int k = 0; k < 8; k++)
        acc[k] += wa[k] * xa + wb[k] * xb + wc[k] * xc + wd[k] * xd;
    }
    for (; j < end; j += ES) {
      int4 ra = erec[j];
      float xa = ord2f(pordc[(long)ra.x * Ci + co]);
      float wa[8];
      basis8(__int_as_float(ra.y) * inv + 0.5f, __int_as_float(ra.z) * inv + 0.5f,
             __int_as_float(ra.w) * inv + 0.5f, wa);
      #pragma unroll
      for (int k = 0; k < 8; k++) acc[k] += wa[k] * xa;
    }
  }
  if (ES > 1) {
    #pragma unroll
    for (int k = 0; k < 8; k++) comb[wv][lane][k] = acc[k];
    __syncthreads();
    if (sub != 0 || !active) return;
    #pragma unroll
    for (int s = 1; s < ES; s++)
      #pragma unroll
      for (int k = 0; k < 8; k++) acc[k] += comb[wv + s][lane][k];
  } else if (!active) return;
  float sc = 1.f / fmaxf((float)len, 1.f);
  long row = (long)d * 9 * Ci;
  #pragma unroll
  for (int k = 0; k < 8; k++) {
    float v = acc[k] * sc;
    unsigned short hu = f2b(v);
    ysh[row + k * Ci + co] = hu;
    ysl[row + k * Ci + co] = f2b(v - b2f(hu));
  }
  unsigned od = pordc[(long)d * Ci + co];
  float xdv = (od == 0u) ? 0.f : ord2f(od);
  unsigned short hu = f2b(xdv);
  ysh[row + 8 * Ci + co] = hu;
  ysl[row + 8 * Ci + co] = f2b(xdv - b2f(hu));
}

// ---------- k_gemmpool: MFMA GEMM + bias + ELU + voxel-pool epilogue ----------
__global__ __launch_bounds__(256)
void k_gemmpool(const unsigned short* __restrict__ ysh, const unsigned short* __restrict__ ysl,
                const unsigned short* __restrict__ Bh, const unsigned short* __restrict__ Bl,
                int M, int N, int K, const float* __restrict__ bias,
                const float* __restrict__ possum, const float* __restrict__ cnt,
                int div, float vs, int G, int NC,
                unsigned* __restrict__ pordn, float* __restrict__ cntn,
                float* __restrict__ possumn, int* __restrict__ nid) {
  __shared__ __align__(16) char smem[20480];
  int nbx = N >> 6;
  int bx = blockIdx.x % nbx, by = blockIdx.x / nbx;
  int m0 = by * 64, n0 = bx * 64;
  f32x4 acc[4] = {};
  mfma_tile(ysh, ysl, Bh, Bl, M, K, m0, n0, 0, K, smem, acc);
  int w = threadIdx.x >> 6, lane = threadIdx.x & 63;
  int row0 = m0 + (w << 4) + ((lane >> 4) << 2);
  int colb = n0 + (lane & 15);
  #pragma unroll
  for (int q = 0; q < 4; q++) {
    int gm = row0 + q;
    float c = cnt[gm];
    float ic = 1.f / fmaxf(c, 1.f);
    float p0 = possum[gm*3] * ic, p1 = possum[gm*3+1] * ic, p2 = possum[gm*3+2] * ic;
    int c0 = clampi((int)floorf(p0 / vs), 0, G - 1);
    int c1 = clampi((int)floorf(p1 / vs), 0, G - 1);
    int c2 = clampi((int)floorf(p2 / vs), 0, G - 1);
    int id = (gm / div) * NC + (c0 * G + c1) * G + c2;
    bool vl = c > 0.f;
    if (bx == 0 && (lane & 15) == 0) {
      nid[gm] = id;
      if (vl) {
        atomicAdd(&cntn[id], 1.f);
        atomicAdd(&possumn[id*3],   p0);
        atomicAdd(&possumn[id*3+1], p1);
        atomicAdd(&possumn[id*3+2], p2);
      }
    }
    if (vl) {
      #pragma unroll
      for (int nt = 0; nt < 4; nt++) {
        int col = colb + nt * 16;
        float v = eluf(acc[nt][q] + bias[col]);
        atomicMax(&pordn[(long)id * N + col], f2ord(v));
      }
    }
  }
}

// ---------- k_gemm4: layer-4 split-K z=4 partials ----------
__global__ __launch_bounds__(256)
void k_gemm4(const unsigned short* __restrict__ ysh, const unsigned short* __restrict__ ysl,
             const unsigned short* __restrict__ Bh, const unsigned short* __restrict__ Bl,
             float* __restrict__ Cp) {
  __shared__ __align__(16) char smem[20480];
  int z = blockIdx.x >> 6, rem = blockIdx.x & 63, bx = rem & 7, by = rem >> 3;
  int m0 = by * 64, n0 = bx * 64;
  f32x4 acc[4] = {};
  mfma_tile(ysh, ysl, Bh, Bl, 500, 2304, m0, n0, z * 576, 576, smem, acc);
  float* Co = Cp + (long)z * 256000;
  int w = threadIdx.x >> 6, lane = threadIdx.x & 63;
  int row0 = m0 + (w << 4) + ((lane >> 4) << 2);
  int colb = n0 + (lane & 15);
  #pragma unroll
  for (int nt = 0; nt < 4; nt++)
    #pragma unroll
    for (int q = 0; q < 4; q++) {
      int gm = row0 + q;
      if (gm < 500) Co[(long)gm * 512 + colb + nt * 16] = acc[nt][q];
    }
}

// ---------- k_reduce4: sum partials + bias + ELU + final MaxPoolingX ----------
__global__ void k_reduce4(const float* __restrict__ Cp, const float* __restrict__ b4,
                          const float* __restrict__ possum3, const float* __restrict__ cnt3,
                          unsigned* __restrict__ xg) {
  int idx = blockIdx.x * 256 + threadIdx.x;
  if (idx >= 256000) return;
  int n = idx >> 9, o = idx & 511;
  float s = Cp[idx] + Cp[idx + 256000] + Cp[idx + 512000] + Cp[idx + 768000];
  float v = eluf(s + b4[o]);
  float c = cnt3[n];
  if (c <= 0.f) return;
  float ic = 1.f / c;
  float p0 = possum3[n*3] * ic, p1 = possum3[n*3+1] * ic, p2 = possum3[n*3+2] * ic;
  int c0 = clampi((int)floorf(p0 / 80.f), 0, 2);
  int c1 = clampi((int)floorf(p1 / 80.f), 0, 2);
  int c2 = clampi((int)floorf(p2 / 80.f), 0, 2);
  int cl = (n / 125) * 64 + (c0 * 3 + c1) * 3 + c2;
  atomicMax(&xg[(long)cl * 512 + o], f2ord(v));
}

// ---------- FC1 (skips the 37/64 always-empty cells) ----------
__global__ __launch_bounds__(128)
void k_fc1(const unsigned* __restrict__ xg_ord, const float* __restrict__ w,
           float* __restrict__ h) {
  int cellhalf = blockIdx.x >> 3, jb = blockIdx.x & 7;
  int cell = cellhalf >> 1, half = cellhalf & 1;
  int j = jb * 128 + threadIdx.x;
  __shared__ float xs[4][256];
  for (int q = threadIdx.x; q < 1024; q += 128) {
    int b = q >> 8, ci = q & 255;
    unsigned o = xg_ord[((b * 64 + cell) << 9) + half * 256 + ci];
    xs[b][ci] = (o == 0u) ? 0.f : ord2f(o);
  }
  __syncthreads();
  float a0 = 0, a1 = 0, a2 = 0, a3 = 0;
  int cbase = cell * 512 + half * 256;
  for (int ci = 0; ci < 256; ci++) {
    float ww = w[(long)(cbase + ci) * 1024 + j];
    a0 += xs[0][ci] * ww; a1 += xs[1][ci] * ww;
    a2 += xs[2][ci] * ww; a3 += xs[3][ci] * ww;
  }
  atomicAdd(&h[j], a0);        atomicAdd(&h[1024 + j], a1);
  atomicAdd(&h[2048 + j], a2); atomicAdd(&h[3072 + j], a3);
}

// ---------- FC2 (fc1 bias+ELU fused) ----------
__global__ void k_fc2(const float* __restrict__ h, const float* __restrict__ fb1,
                      const float* __restrict__ w, const float* __restrict__ b,
                      float* __restrict__ out) {
  int bb = blockIdx.x, t = threadIdx.x;
  float a = 0;
  for (int j = t; j < 1024; j += 256) a += eluf(h[bb * 1024 + j] + fb1[j]) * w[j];
  for (int off = 32; off; off >>= 1) a += __shfl_down(a, off, 64);
  __shared__ float red[4];
  int lane = t & 63, wv = t >> 6;
  if (lane == 0) red[wv] = a;
  __syncthreads();
  if (t == 0) out[bb] = eluf(red[0] + red[1] + red[2] + red[3] + b[0]);
}

// =======================================================================
extern "C" void kernel_launch(void* const* d_in, const int* in_sizes, int n_in,
                              void* d_out, int out_size, void* d_ws, size_t ws_size,
                              hipStream_t stream) {
  const float* x0   = (const float*)d_in[0];
  const float* pos0 = (const float*)d_in[1];
  const int*   ei   = (const int*)d_in[2];
  const float* W1 = (const float*)d_in[4],  *Wr1 = (const float*)d_in[5],  *b1 = (const float*)d_in[6];
  const float* W2 = (const float*)d_in[7],  *Wr2 = (const float*)d_in[8],  *b2 = (const float*)d_in[9];
  const float* W3 = (const float*)d_in[10], *Wr3 = (const float*)d_in[11], *b3 = (const float*)d_in[12];
  const float* W4 = (const float*)d_in[13], *Wr4 = (const float*)d_in[14], *b4 = (const float*)d_in[15];
  const float* fw1 = (const float*)d_in[16], *fb1 = (const float*)d_in[17];
  const float* fw2 = (const float*)d_in[18], *fb2 = (const float*)d_in[19];
  float* out = (float*)d_out;
  const int* src0 = ei;
  const int* dst0 = ei + E0;

  char* ws = (char*)d_ws;
  size_t off = 0;
  auto alloc = [&](size_t bytes) -> void* {
    off = (off + 255) & ~(size_t)255;
    void* q = ws + off; off += bytes; return q;
  };
  // non-zeroed buffers
  int4* erec0u = (int4*)alloc((size_t)E0 * 16);
  int4* erec_s = (int4*)alloc((size_t)E0 * 16);
  int4* eu_a   = (int4*)alloc((size_t)E0 * 16);
  int4* eu_b   = (int4*)alloc((size_t)E0 * 16);
  int* du_a = (int*)alloc(E0 * 4);
  int* du_b = (int*)alloc(E0 * 4);
  int* nid  = (int*)alloc(NL0 * 4);
  int* rowbeg = (int*)alloc(NL0 * 4);
  int* rowlen = (int*)alloc(NL0 * 4);
  int* cursor = (int*)alloc(NL0 * 4);
  float* ysg = (float*)alloc((size_t)NL0 * 8 * 4);
  unsigned short* ysh = (unsigned short*)alloc((size_t)NL1 * 576 * 2);
  unsigned short* ysl = (unsigned short*)alloc((size_t)NL1 * 576 * 2);
  float* wc1 = (float*)alloc(576 * 4);
  unsigned short* w2h = (unsigned short*)alloc((size_t)576 * 128 * 2);
  unsigned short* w2l = (unsigned short*)alloc((size_t)576 * 128 * 2);
  unsigned short* w3h = (unsigned short*)alloc((size_t)1152 * 256 * 2);
  unsigned short* w3l = (unsigned short*)alloc((size_t)1152 * 256 * 2);
  unsigned short* w4h = (unsigned short*)alloc((size_t)2304 * 512 * 2);
  unsigned short* w4l = (unsigned short*)alloc((size_t)2304 * 512 * 2);
  float* Cp = (float*)alloc((size_t)4 * 256000 * 4);
  // zero region (single memset per call)
  char* z0 = (char*)alloc(0);
  unsigned* pord1 = (unsigned*)alloc((size_t)NL1 * 64 * 4);
  unsigned* pord2 = (unsigned*)alloc((size_t)NL2 * 128 * 4);
  unsigned* pord3 = (unsigned*)alloc((size_t)NL3 * 256 * 4);
  unsigned* xg    = (unsigned*)alloc((size_t)4 * 64 * 512 * 4);
  float* cnt1 = (float*)alloc(NL1 * 4);
  float* cnt2 = (float*)alloc(NL2 * 4);
  float* cnt3 = (float*)alloc(NL3 * 4);
  float* possum1 = (float*)alloc(NL1 * 12);
  float* possum2 = (float*)alloc(NL2 * 12);
  float* possum3 = (float*)alloc(NL3 * 12);
  size_t bm1w = ((size_t)NL1 * NL1 + 31) / 32;
  size_t bm2w = ((size_t)NL2 * NL2 + 31) / 32;
  size_t bm3w = ((size_t)NL3 * NL3 + 31) / 32;
  unsigned* bm1 = (unsigned*)alloc(bm1w * 4);
  unsigned* bm2 = (unsigned*)alloc(bm2w * 4);
  unsigned* bm3 = (unsigned*)alloc(bm3w * 4);
  int* degi = (int*)alloc(NL0 * 4);
  float* mbuf = (float*)alloc(64);
  int* ecnt = (int*)(mbuf + 8);
  int* ctr  = (int*)(mbuf + 12);
  float* h = (float*)alloc(4096 * 4);
  char* zend = (char*)alloc(0);
  size_t zbytes = (size_t)(zend - z0);
  (void)ws_size; (void)in_sizes; (void)n_in; (void)out_size;

  auto cdiv = [](long a, long b) { return (int)((a + b - 1) / b); };

  hipMemsetAsync(z0, 0, zbytes, stream);

  // L0: deg + absmax + edge records + weight prep
  k_prep<<<512, 256, 0, stream>>>(src0, dst0, pos0, x0, degi, erec0u, mbuf,
                                  W1, Wr1, wc1, W2, Wr2, W3, Wr3, W4, Wr4,
                                  w2h, w2l, w3h, w3l, w4h, w4l);
  k_alloc<<<cdiv(NL0, 256), 256, 0, stream>>>(degi, rowbeg, rowlen, cursor, ctr + 0, NL0);
  k_scat<<<512, 256, 0, stream>>>(erec0u, dst0, nullptr, E0, cursor, erec_s);
  // layer 1 + pool 1 (two-kernel: coalesced row walk, then wave-per-node matvec)
  k_l1a<<<cdiv(NL0, 32), 256, 0, stream>>>(erec_s, rowbeg, rowlen, mbuf, ysg);
  k_l1b<<<cdiv(NL0, 4), 256, 0, stream>>>(ysg, x0, pos0, wc1, b1, pord1, cnt1, possum1, nid);
  k_pedge<<<512, 256, 0, stream>>>(nullptr, src0, dst0, nullptr, E0, nid, NL1, bm1,
                                   eu_a, du_a, ecnt + 0, degi, possum1, cnt1, mbuf + 1);
  k_alloc<<<cdiv(NL1, 256), 256, 0, stream>>>(degi, rowbeg, rowlen, cursor, ctr + 1, NL1);
  k_scat<<<512, 256, 0, stream>>>(eu_a, du_a, ecnt + 0, E0, cursor, erec_s);
  // layer 2 + pool 2   (gather: ES=1, 6912 jobs)
  k_gather<1><<<cdiv(NL1, 4), 256, 0, stream>>>(pord1, erec_s, rowbeg, rowlen, mbuf + 1,
                                                ysh, ysl, NL1, 64, 1);
  k_gemmpool<<<(128 / 64) * (NL1 / 64), 256, 0, stream>>>(
      ysh, ysl, w2h, w2l, NL1, 128, 576, b2, possum1, cnt1,
      1728, 30.f, 8, 512, pord2, cnt2, possum2, nid);
  k_pedge<<<512, 256, 0, stream>>>(eu_a, nullptr, du_a, ecnt + 0, E0, nid, NL2, bm2,
                                   eu_b, du_b, ecnt + 1, degi, possum2, cnt2, mbuf + 2);
  k_alloc<<<cdiv(NL2, 256), 256, 0, stream>>>(degi, rowbeg, rowlen, cursor, ctr + 2, NL2);
  k_scat<<<512, 256, 0, stream>>>(eu_b, du_b, ecnt + 1, E0, cursor, erec_s);
  // layer 3 + pool 3   (gather: ES=2)
  k_gather<2><<<cdiv(NL2 * 2 * 2, 4), 256, 0, stream>>>(pord2, erec_s, rowbeg, rowlen, mbuf + 2,
                                                        ysh, ysl, NL2, 128, 2);
  k_gemmpool<<<(256 / 64) * (NL2 / 64), 256, 0, stream>>>(
      ysh, ysl, w3h, w3l, NL2, 256, 1152, b3, possum2, cnt2,
      512, 50.f, 5, 125, pord3, cnt3, possum3, nid);
  k_pedge<<<512, 256, 0, stream>>>(eu_b, nullptr, du_b, ecnt + 1, E0, nid, NL3, bm3,
                                   eu_a, du_a, ecnt + 2, degi, possum3, cnt3, mbuf + 3);
  k_alloc<<<cdiv(NL3, 256), 256, 0, stream>>>(degi, rowbeg, rowlen, cursor, ctr + 3, NL3);
  k_scat<<<512, 256, 0, stream>>>(eu_a, du_a, ecnt + 2, E0, cursor, erec_s);
  // layer 4 + final pool   (gather: ES=4)
  k_gather<4><<<cdiv(NL3 * 4 * 4, 4), 256, 0, stream>>>(pord3, erec_s, rowbeg, rowlen, mbuf + 3,
                                                        ysh, ysl, NL3, 256, 4);
  k_gemm4<<<256, 256, 0, stream>>>(ysh, ysl, w4h, w4l, Cp);
  k_reduce4<<<cdiv(256000, 256), 256, 0, stream>>>(Cp, b4, possum3, cnt3, xg);
  // FC head
  k_fc1<<<27 * 2 * 8, 128, 0, stream>>>(xg, fw1, h);
  k_fc2<<<4, 256, 0, stream>>>(h, fb1, fw2, fb2, out);
}